// Round 3
// baseline (1474.421 us; speedup 1.0000x reference)
//
#include <hip/hip_runtime.h>
#include <hip/hip_bf16.h>

using bf16 = __hip_bfloat16;
typedef __attribute__((ext_vector_type(8))) short short8;
typedef __attribute__((ext_vector_type(4))) float float4v;

constexpr int NTOK = 131072;  // 2*256*256

// ---------------- workspace layout (bytes) ----------------
constexpr size_t OFF_Y    = 0;           // bf16 [2][65536][192]  50,331,648
constexpr size_t OFF_T1   = 50331648;    // f32  [131072][24]     12,582,912
constexpr size_t OFF_T2   = 62914560;    // f32  [131072][24]     12,582,912
constexpr size_t OFF_S0   = 75497472;    // f32  [2][192]
constexpr size_t OFF_SG   = 75499008;    // f32  [2][192]
constexpr size_t OFF_WQKV = 75500544;    // bf16 [576][192]       221,184
constexpr size_t OFF_WPRJ = 75721728;    // bf16 [192][192]        73,728
constexpr size_t OFF_WFC1 = 75795456;    // bf16 [768][192]       294,912
constexpr size_t OFF_WFC2 = 76090368;    // bf16 [192][768]       294,912
constexpr size_t OFF_C1WB = 76385280;    // bf16 [32][192]         12,288 (rows 24..31 zero)
constexpr size_t WS_NEEDED = 76397568;

__device__ __forceinline__ int region256(int t) { return t < 248 ? 0 : (t < 252 ? 1 : 2); }

__device__ __forceinline__ short8 lds8(const bf16* p) {
  return *reinterpret_cast<const short8*>(p);
}
__device__ __forceinline__ short8 glb8(const bf16* p) {
  return *reinterpret_cast<const short8*>(p);
}

// ---------------- fp32 -> bf16 weight convert ----------------
__global__ __launch_bounds__(256) void k_f2b(const float* __restrict__ s, bf16* __restrict__ d, int n) {
  int i = blockIdx.x * 256 + threadIdx.x;
  if (i < n) d[i] = __float2bfloat16(s[i]);
}

// ---------------- LCE conv3x3 24->24, LDS-tiled ----------------
__global__ __launch_bounds__(256) void k_lce2t(const float* __restrict__ t1, const float* __restrict__ w,
                                               const float* __restrict__ bia, float* __restrict__ t2) {
  __shared__ float halo[18 * 18 * 25];
  __shared__ float wlds[5184];
  int bid = blockIdx.x;  // 512 = 2 * 16 * 16
  int b = bid >> 8;
  int rem = bid & 255;
  int ty0 = ((rem >> 4) & 15) * 16, tx0 = (rem & 15) * 16;
  for (int idx = threadIdx.x; idx < 5184; idx += 256) wlds[idx] = w[idx];
  for (int idx = threadIdx.x; idx < 18 * 18 * 24; idx += 256) {
    int ch = idx % 24;
    int pp = idx / 24;
    int hy = pp / 18, hx = pp - hy * 18;
    int gy = ty0 + hy - 1, gx = tx0 + hx - 1;
    float v = 0.f;
    if (gy >= 0 && gy < 256 && gx >= 0 && gx < 256)
      v = t1[((size_t)(b << 16) + (gy << 8) + gx) * 24 + ch];
    halo[pp * 25 + ch] = v;
  }
  __syncthreads();
  int py = threadIdx.x >> 4, px = threadIdx.x & 15;
  float acc[24];
#pragma unroll
  for (int ro = 0; ro < 24; ++ro) acc[ro] = bia[ro];
  for (int ky = 0; ky < 3; ++ky) {
    for (int kx = 0; kx < 3; ++kx) {
      int base = ((py + ky) * 18 + px + kx) * 25;
      float inb[24];
#pragma unroll
      for (int ri = 0; ri < 24; ++ri) inb[ri] = halo[base + ri];
      int wo = ky * 3 + kx;
#pragma unroll
      for (int ro = 0; ro < 24; ++ro) {
        float a = acc[ro];
#pragma unroll
        for (int ri = 0; ri < 24; ++ri) a += inb[ri] * wlds[ro * 216 + ri * 9 + wo];
        acc[ro] = a;
      }
    }
  }
  size_t pix = (size_t)(b << 16) + ((ty0 + py) << 8) + tx0 + px;
#pragma unroll
  for (int ro = 0; ro < 24; ++ro) t2[pix * 24 + ro] = acc[ro];
}

// ---------------- LCE conv1x1 24->192 + LeakyReLU -> y (bf16) ----------------
__global__ __launch_bounds__(256) void k_lce3(const float* __restrict__ t2, const float* __restrict__ w,
                                              const float* __restrict__ bia, bf16* __restrict__ y) {
  size_t tid = (size_t)blockIdx.x * 256 + threadIdx.x;
  int c = (int)(tid % 192);
  size_t pix = tid / 192;
  const float* ir = t2 + pix * 24;
  const float* wr = w + c * 24;
  float acc = bia[c];
  for (int ri = 0; ri < 24; ++ri) acc += ir[ri] * wr[ri];
  if (acc < 0.f) acc *= 0.2f;
  y[tid] = __float2bfloat16(acc);
}

// ---------------- global avg pool partial sums ----------------
__global__ __launch_bounds__(192) void k_pool(const bf16* __restrict__ y, float* __restrict__ s0) {
  int b = blockIdx.x >> 10;
  int chunk = blockIdx.x & 1023;
  int c = threadIdx.x;
  size_t base = ((size_t)b * 65536 + chunk * 64) * 192;
  float acc = 0.f;
  for (int p = 0; p < 64; ++p) acc += __bfloat162float(y[base + (size_t)p * 192 + c]);
  atomicAdd(&s0[b * 192 + c], acc);
}

// ---------------- SE gate ----------------
__global__ __launch_bounds__(256) void k_se(const float* __restrict__ s0, const float* __restrict__ w1,
                                            const float* __restrict__ w2, float* __restrict__ sg) {
  __shared__ float mean[192];
  __shared__ float t[24];
  int b = blockIdx.x;
  int tid = threadIdx.x;
  if (tid < 192) mean[tid] = s0[b * 192 + tid] * (1.f / 65536.f);
  __syncthreads();
  if (tid < 24) {
    float a = 0.f;
    for (int c = 0; c < 192; ++c) a += mean[c] * w1[tid * 192 + c];
    t[tid] = fmaxf(a, 0.f);
  }
  __syncthreads();
  if (tid < 192) {
    float a = 0.f;
    for (int r = 0; r < 24; ++r) a += t[r] * w2[tid * 24 + r];
    sg[b * 192 + tid] = 1.f / (1.f + expf(-a));
  }
}

// ---------------- chunked fused attention (+ LCE conv1) ----------------
// 2048 blocks (one per window), 256 threads, wave w owns rows 16w..16w+15.
// Head-group chunking: 3 chunks x 2 heads. Per chunk only K/V/O thirds live
// in LDS -> 32,768 B total -> 4 blocks/CU (was 81,920 -> 2 blocks/CU,
// occupancy 23.7%, latency-bound). proj accumulates partials in registers
// across chunks (K-dim of proj = O cols, exact). LN staging transiently
// reuses the O+K+V regions (dead until chunk 0 writes; barrier-protected).
// All LDS regions XOR-swizzled (byte ^= (row&7)<<4): conflict-free b128 reads.
// Regions (byte offsets, 64 rows x 128B each except staging):
//   O3  @0      [64][64] bf16  (per-wave O third; staging rows overlap)
//   KL3 @8192   [64 tok][64 ch] bf16
//   VT3 @16384  [64 ch][64 tok] bf16
//   PS3 @24576  [64][64]  bf16  (per-wave Q/P scratch)
//   STG = [64][192] bf16 spanning 0..24576 (LN rows, transient)
__device__ __forceinline__ int stg_b(int r, int c) { return (r * 384 + c * 2) ^ ((r & 7) << 4); }
__device__ __forceinline__ int o3_b (int r, int c) { return (r * 128 + c * 2) ^ ((r & 7) << 4); }
__device__ __forceinline__ int kl3_b(int r, int c) { return 8192  + ((r * 128 + c * 2) ^ ((r & 7) << 4)); }
__device__ __forceinline__ int vt3_b(int r, int c) { return 16384 + ((r * 128 + c * 2) ^ ((r & 7) << 4)); }
__device__ __forceinline__ int ps3_b(int r, int c) { return 24576 + ((r * 128 + c * 2) ^ ((r & 7) << 4)); }

__device__ __forceinline__ short8 lds8o(const char* sm, int byteoff) {
  return *reinterpret_cast<const short8*>(sm + byteoff);
}
__device__ __forceinline__ void st16(char* sm, int byteoff, bf16 v) {
  *reinterpret_cast<bf16*>(sm + byteoff) = v;
}

__global__ __launch_bounds__(256, 4) void k_attn2(const float* __restrict__ x, const float* __restrict__ g,
                                                  const float* __restrict__ bb, const bf16* __restrict__ wq,
                                                  const float* __restrict__ qkvb, const float* __restrict__ rpb,
                                                  const bf16* __restrict__ wp, const float* __restrict__ projb,
                                                  const bf16* __restrict__ c1wb, const float* __restrict__ c1b,
                                                  float* __restrict__ t1, float* __restrict__ x1out) {
  __shared__ char sm[32768];

  int win = blockIdx.x;
  int b = win >> 10;
  int wrem = win & 1023;
  int wh = wrem >> 5, ww = wrem & 31;
  int tid = threadIdx.x;
  int wave = tid >> 6, lane = tid & 63;
  int colB = lane & 15, grp = lane >> 4;
  const float scale = 0.17677669529663687f;  // 1/sqrt(32)

  // ---- Phase 1: LN over this wave's 16 tokens (gather with roll -4) -> staging
  for (int t = 0; t < 16; ++t) {
    int tok = wave * 16 + t;
    int i = tok >> 3, j = tok & 7;
    int hp = (wh * 8 + i + 4) & 255;
    int wpp = (ww * 8 + j + 4) & 255;
    const float* xr = x + (((size_t)b << 16) + (hp << 8) + wpp) * 192;
    float v0 = xr[lane], v1 = xr[lane + 64], v2 = xr[lane + 128];
    float s = v0 + v1 + v2;
    for (int o = 32; o > 0; o >>= 1) s += __shfl_down(s, o);
    s = __shfl(s, 0);
    float m = s * (1.f / 192.f);
    float d0 = v0 - m, d1 = v1 - m, d2 = v2 - m;
    float q = d0 * d0 + d1 * d1 + d2 * d2;
    for (int o = 32; o > 0; o >>= 1) q += __shfl_down(q, o);
    q = __shfl(q, 0);
    float inv = rsqrtf(q * (1.f / 192.f) + 1e-5f);
    st16(sm, stg_b(tok, lane),       __float2bfloat16(d0 * inv * g[lane]       + bb[lane]));
    st16(sm, stg_b(tok, lane + 64),  __float2bfloat16(d1 * inv * g[lane + 64]  + bb[lane + 64]));
    st16(sm, stg_b(tok, lane + 128), __float2bfloat16(d2 * inv * g[lane + 128] + bb[lane + 128]));
  }

  // A-fragments of LN rows (same-wave LDS write->read, DS pipe in-order)
  short8 axw[6];
#pragma unroll
  for (int kk = 0; kk < 6; ++kk) axw[kk] = lds8o(sm, stg_b(wave * 16 + colB, kk * 32 + 8 * grp));
  __syncthreads();  // staging consumed by ALL waves before chunk-0 K/V overwrite

  // row constants for bias/mask
  int l1r[4], i1r[4], j1r[4];
#pragma unroll
  for (int r = 0; r < 4; ++r) {
    int n = wave * 16 + 4 * grp + r;
    i1r[r] = n >> 3; j1r[r] = n & 7;
    l1r[r] = region256(wh * 8 + i1r[r]) * 3 + region256(ww * 8 + j1r[r]);
  }

  float4v projacc[12] = {{0,0,0,0},{0,0,0,0},{0,0,0,0},{0,0,0,0},{0,0,0,0},{0,0,0,0},
                         {0,0,0,0},{0,0,0,0},{0,0,0,0},{0,0,0,0},{0,0,0,0},{0,0,0,0}};

  for (int gch = 0; gch < 3; ++gch) {  // chunk = heads {2g, 2g+1} = qkv cols 64g..64g+63
    // ---- QKV GEMM for this chunk (B-fragments straight from global bf16 weights)
    float qreg[16];
    {  // Q
      float4v qa[4] = {{0,0,0,0},{0,0,0,0},{0,0,0,0},{0,0,0,0}};
#pragma unroll
      for (int kk = 0; kk < 6; ++kk) {
#pragma unroll
        for (int jt = 0; jt < 4; ++jt) {
          int wrow = gch * 64 + jt * 16 + colB;
          qa[jt] = __builtin_amdgcn_mfma_f32_16x16x32_bf16(axw[kk], glb8(wq + (size_t)wrow * 192 + kk * 32 + 8 * grp), qa[jt], 0, 0, 0);
        }
      }
#pragma unroll
      for (int jt = 0; jt < 4; ++jt) {
        float bias = qkvb[gch * 64 + jt * 16 + colB];
#pragma unroll
        for (int r = 0; r < 4; ++r) qreg[jt * 4 + r] = (qa[jt][r] + bias) * scale;
      }
    }
    {  // K -> KL3 (rows = own tokens)
      float4v ka[4] = {{0,0,0,0},{0,0,0,0},{0,0,0,0},{0,0,0,0}};
#pragma unroll
      for (int kk = 0; kk < 6; ++kk) {
#pragma unroll
        for (int jt = 0; jt < 4; ++jt) {
          int wrow = 192 + gch * 64 + jt * 16 + colB;
          ka[jt] = __builtin_amdgcn_mfma_f32_16x16x32_bf16(axw[kk], glb8(wq + (size_t)wrow * 192 + kk * 32 + 8 * grp), ka[jt], 0, 0, 0);
        }
      }
#pragma unroll
      for (int jt = 0; jt < 4; ++jt) {
        float bias = qkvb[192 + gch * 64 + jt * 16 + colB];
#pragma unroll
        for (int r = 0; r < 4; ++r)
          st16(sm, kl3_b(wave * 16 + 4 * grp + r, jt * 16 + colB), __float2bfloat16(ka[jt][r] + bias));
      }
    }
    {  // V -> VT3 (transposed: rows = local channel, cols = own tokens)
      float4v va[4] = {{0,0,0,0},{0,0,0,0},{0,0,0,0},{0,0,0,0}};
#pragma unroll
      for (int kk = 0; kk < 6; ++kk) {
#pragma unroll
        for (int jt = 0; jt < 4; ++jt) {
          int wrow = 384 + gch * 64 + jt * 16 + colB;
          va[jt] = __builtin_amdgcn_mfma_f32_16x16x32_bf16(axw[kk], glb8(wq + (size_t)wrow * 192 + kk * 32 + 8 * grp), va[jt], 0, 0, 0);
        }
      }
#pragma unroll
      for (int jt = 0; jt < 4; ++jt) {
        float bias = qkvb[384 + gch * 64 + jt * 16 + colB];
#pragma unroll
        for (int r = 0; r < 4; ++r)
          st16(sm, vt3_b(jt * 16 + colB, wave * 16 + 4 * grp + r), __float2bfloat16(va[jt][r] + bias));
      }
    }
    if (gch == 0) {  // conv1 (LCE): 2 N-tiles, weights zero-padded to 32 rows
      float4v acc[2] = {{0,0,0,0},{0,0,0,0}};
#pragma unroll
      for (int kk = 0; kk < 6; ++kk) {
#pragma unroll
        for (int j = 0; j < 2; ++j) {
          int row = j * 16 + colB;
          acc[j] = __builtin_amdgcn_mfma_f32_16x16x32_bf16(axw[kk], glb8(c1wb + (size_t)row * 192 + kk * 32 + 8 * grp), acc[j], 0, 0, 0);
        }
      }
#pragma unroll
      for (int j = 0; j < 2; ++j) {
        int ch = j * 16 + colB;
        if (ch < 24) {
          float bias = c1b[ch];
#pragma unroll
          for (int r = 0; r < 4; ++r) {
            int tok = wave * 16 + 4 * grp + r;
            int i = tok >> 3, jj = tok & 7;
            int hp = (wh * 8 + i + 4) & 255;
            int wpp = (ww * 8 + jj + 4) & 255;
            size_t pix = ((size_t)b << 16) + (hp << 8) + wpp;
            t1[pix * 24 + ch] = acc[j][r] + bias;
          }
        }
      }
    }
    __syncthreads();  // K/V of this chunk visible to all waves

    // ---- attention for the chunk's 2 heads (PS/O per-wave private)
#pragma unroll
    for (int hh = 0; hh < 2; ++hh) {
      int h = 2 * gch + hh;
      // Q tile -> scratch -> A-frag
#pragma unroll
      for (int t = 0; t < 2; ++t)
#pragma unroll
        for (int r = 0; r < 4; ++r)
          st16(sm, ps3_b(wave * 16 + 4 * grp + r, t * 16 + colB), __float2bfloat16(qreg[(hh * 2 + t) * 4 + r]));
      short8 aq = lds8o(sm, ps3_b(wave * 16 + colB, 8 * grp));

      float4v s[4];
#pragma unroll
      for (int nt = 0; nt < 4; ++nt) {
        short8 bk = lds8o(sm, kl3_b(nt * 16 + colB, hh * 32 + 8 * grp));
        float4v z = {0, 0, 0, 0};
        s[nt] = __builtin_amdgcn_mfma_f32_16x16x32_bf16(aq, bk, z, 0, 0, 0);
      }
#pragma unroll
      for (int nt = 0; nt < 4; ++nt) {
        int m = nt * 16 + colB;
        int i2 = m >> 3, j2 = m & 7;
        int l2 = region256(wh * 8 + i2) * 3 + region256(ww * 8 + j2);
#pragma unroll
        for (int r = 0; r < 4; ++r) {
          float bias = rpb[((i1r[r] - i2 + 7) * 15 + (j1r[r] - j2 + 7)) * 6 + h];
          s[nt][r] += bias + (l1r[r] != l2 ? -100.f : 0.f);
        }
      }
#pragma unroll
      for (int r = 0; r < 4; ++r) {
        float mx = fmaxf(fmaxf(s[0][r], s[1][r]), fmaxf(s[2][r], s[3][r]));
        mx = fmaxf(mx, __shfl_xor(mx, 1));
        mx = fmaxf(mx, __shfl_xor(mx, 2));
        mx = fmaxf(mx, __shfl_xor(mx, 4));
        mx = fmaxf(mx, __shfl_xor(mx, 8));
        float e0 = __expf(s[0][r] - mx), e1 = __expf(s[1][r] - mx);
        float e2 = __expf(s[2][r] - mx), e3 = __expf(s[3][r] - mx);
        float sum = e0 + e1 + e2 + e3;
        sum += __shfl_xor(sum, 1);
        sum += __shfl_xor(sum, 2);
        sum += __shfl_xor(sum, 4);
        sum += __shfl_xor(sum, 8);
        float inv = 1.f / sum;
        int row = wave * 16 + 4 * grp + r;
        st16(sm, ps3_b(row, 0 * 16 + colB), __float2bfloat16(e0 * inv));
        st16(sm, ps3_b(row, 1 * 16 + colB), __float2bfloat16(e1 * inv));
        st16(sm, ps3_b(row, 2 * 16 + colB), __float2bfloat16(e2 * inv));
        st16(sm, ps3_b(row, 3 * 16 + colB), __float2bfloat16(e3 * inv));
      }
      short8 ap0 = lds8o(sm, ps3_b(wave * 16 + colB, 0 * 32 + 8 * grp));
      short8 ap1 = lds8o(sm, ps3_b(wave * 16 + colB, 1 * 32 + 8 * grp));

      float4v o0 = {0, 0, 0, 0}, o1 = {0, 0, 0, 0};
      o0 = __builtin_amdgcn_mfma_f32_16x16x32_bf16(ap0, lds8o(sm, vt3_b(hh * 32 + colB, 8 * grp)), o0, 0, 0, 0);
      o0 = __builtin_amdgcn_mfma_f32_16x16x32_bf16(ap1, lds8o(sm, vt3_b(hh * 32 + colB, 32 + 8 * grp)), o0, 0, 0, 0);
      o1 = __builtin_amdgcn_mfma_f32_16x16x32_bf16(ap0, lds8o(sm, vt3_b(hh * 32 + 16 + colB, 8 * grp)), o1, 0, 0, 0);
      o1 = __builtin_amdgcn_mfma_f32_16x16x32_bf16(ap1, lds8o(sm, vt3_b(hh * 32 + 16 + colB, 32 + 8 * grp)), o1, 0, 0, 0);
#pragma unroll
      for (int r = 0; r < 4; ++r) {
        int row = wave * 16 + 4 * grp + r;
        st16(sm, o3_b(row, hh * 32 + colB),      __float2bfloat16(o0[r]));
        st16(sm, o3_b(row, hh * 32 + 16 + colB), __float2bfloat16(o1[r]));
      }
    }

    // ---- proj partial over this chunk's 64 O-cols (own rows; no barrier needed)
    {
      short8 ao0 = lds8o(sm, o3_b(wave * 16 + colB, 8 * grp));
      short8 ao1 = lds8o(sm, o3_b(wave * 16 + colB, 32 + 8 * grp));
#pragma unroll
      for (int j = 0; j < 12; ++j) {
        int col = j * 16 + colB;
        projacc[j] = __builtin_amdgcn_mfma_f32_16x16x32_bf16(ao0, glb8(wp + (size_t)col * 192 + gch * 64 + 8 * grp), projacc[j], 0, 0, 0);
        projacc[j] = __builtin_amdgcn_mfma_f32_16x16x32_bf16(ao1, glb8(wp + (size_t)col * 192 + gch * 64 + 32 + 8 * grp), projacc[j], 0, 0, 0);
      }
    }
    __syncthreads();  // all waves done reading K/V before next chunk overwrites
  }

  // ---- Phase 4: proj bias + reverse-shift scatter + residual
#pragma unroll
  for (int j = 0; j < 12; ++j) {
    int col = j * 16 + colB;
    float bias = projb[col];
#pragma unroll
    for (int r = 0; r < 4; ++r) {
      int n = wave * 16 + 4 * grp + r;
      int i = n >> 3, jj = n & 7;
      int hd2 = (wh * 8 + i + 4) & 255;
      int wd2 = (ww * 8 + jj + 4) & 255;
      size_t p = (((size_t)b << 16) + (hd2 << 8) + wd2) * 192 + col;
      x1out[p] = x[p] + projacc[j][r] + bias;
    }
  }
}

// ---------------- MFMA MLP: LN2 + fc1 + GELU + fc2 + residual (in-place) ----------------
// Halved hh buffer (fc1/fc2 split into two 384-col halves, fc2 partials in regs)
// + XOR swizzle instead of padding: LDS 62,464 -> 36,864 B -> 4 blocks/CU.
__device__ __forceinline__ int xl_b(int r, int c) { return (r * 384 + c * 2) ^ ((r & 7) << 4); }
__device__ __forceinline__ int hh_b(int r, int c) { return 12288 + ((r * 768 + c * 2) ^ ((r & 7) << 4)); }

__global__ __launch_bounds__(256, 4) void k_mlp_mfma(float* __restrict__ x1, const float* __restrict__ g,
                                                     const float* __restrict__ bb, const bf16* __restrict__ w1,
                                                     const float* __restrict__ b1, const bf16* __restrict__ w2,
                                                     const float* __restrict__ b2) {
  __shared__ char sm[36864];
  int tid = threadIdx.x;
  int wave = tid >> 6, lane = tid & 63;
  int colB = lane & 15, grp = lane >> 4;
  size_t tokbase = (size_t)blockIdx.x * 32;

  for (int t = wave; t < 32; t += 4) {
    const float* xr = x1 + (tokbase + t) * 192;
    float v0 = xr[lane], v1 = xr[lane + 64], v2 = xr[lane + 128];
    float s = v0 + v1 + v2;
    for (int o = 32; o > 0; o >>= 1) s += __shfl_down(s, o);
    s = __shfl(s, 0);
    float m = s * (1.f / 192.f);
    float d0 = v0 - m, d1 = v1 - m, d2 = v2 - m;
    float qq = d0 * d0 + d1 * d1 + d2 * d2;
    for (int o = 32; o > 0; o >>= 1) qq += __shfl_down(qq, o);
    qq = __shfl(qq, 0);
    float inv = rsqrtf(qq * (1.f / 192.f) + 1e-5f);
    st16(sm, xl_b(t, lane),       __float2bfloat16(d0 * inv * g[lane]       + bb[lane]));
    st16(sm, xl_b(t, lane + 64),  __float2bfloat16(d1 * inv * g[lane + 64]  + bb[lane + 64]));
    st16(sm, xl_b(t, lane + 128), __float2bfloat16(d2 * inv * g[lane + 128] + bb[lane + 128]));
  }
  __syncthreads();

  short8 a1f[6][2];
#pragma unroll
  for (int kk = 0; kk < 6; ++kk) {
    a1f[kk][0] = lds8o(sm, xl_b(colB, kk * 32 + 8 * grp));
    a1f[kk][1] = lds8o(sm, xl_b(16 + colB, kk * 32 + 8 * grp));
  }

  float4v d0a[3] = {{0,0,0,0},{0,0,0,0},{0,0,0,0}};
  float4v d1a[3] = {{0,0,0,0},{0,0,0,0},{0,0,0,0}};
  int ntb = wave * 3;

  for (int ph = 0; ph < 2; ++ph) {
    if (ph) __syncthreads();  // prior fc2 reads of hh complete before overwrite
    // fc1 half: 24 local tiles (384 cols), 6 per wave
    for (int nn = 0; nn < 6; ++nn) {
      int ntl = wave * 6 + nn;                 // local tile 0..23
      int colg = ph * 384 + ntl * 16 + colB;   // global fc1 col
      float4v c0 = {0, 0, 0, 0}, c1 = {0, 0, 0, 0};
#pragma unroll
      for (int kk = 0; kk < 6; ++kk) {
        short8 bw = glb8(w1 + (size_t)colg * 192 + kk * 32 + 8 * grp);
        c0 = __builtin_amdgcn_mfma_f32_16x16x32_bf16(a1f[kk][0], bw, c0, 0, 0, 0);
        c1 = __builtin_amdgcn_mfma_f32_16x16x32_bf16(a1f[kk][1], bw, c1, 0, 0, 0);
      }
      float bias = b1[colg];
      int coll = ntl * 16 + colB;
#pragma unroll
      for (int r = 0; r < 4; ++r) {
        float v0 = c0[r] + bias;
        float v1 = c1[r] + bias;
        v0 = v0 * 0.5f * (1.f + erff(v0 * 0.70710678118654752f));
        v1 = v1 * 0.5f * (1.f + erff(v1 * 0.70710678118654752f));
        st16(sm, hh_b(4 * grp + r, coll), __float2bfloat16(v0));
        st16(sm, hh_b(16 + 4 * grp + r, coll), __float2bfloat16(v1));
      }
    }
    __syncthreads();
    // fc2 partial over this half's 384 K
    for (int kk = 0; kk < 12; ++kk) {
      int kol = kk * 32 + 8 * grp;
      int kog = ph * 384 + kol;
      short8 h0 = lds8o(sm, hh_b(colB, kol));
      short8 h1 = lds8o(sm, hh_b(16 + colB, kol));
#pragma unroll
      for (int j = 0; j < 3; ++j) {
        short8 bw = glb8(w2 + (size_t)((ntb + j) * 16 + colB) * 768 + kog);
        d0a[j] = __builtin_amdgcn_mfma_f32_16x16x32_bf16(h0, bw, d0a[j], 0, 0, 0);
        d1a[j] = __builtin_amdgcn_mfma_f32_16x16x32_bf16(h1, bw, d1a[j], 0, 0, 0);
      }
    }
  }

#pragma unroll
  for (int j = 0; j < 3; ++j) {
    int col = (ntb + j) * 16 + colB;
    float bias = b2[col];
#pragma unroll
    for (int r = 0; r < 4; ++r) {
      size_t p0 = (tokbase + 4 * grp + r) * 192 + col;
      size_t p1 = (tokbase + 16 + 4 * grp + r) * 192 + col;
      x1[p0] += d0a[j][r] + bias;
      x1[p1] += d1a[j][r] + bias;
    }
  }
}

// ---------------- out += y * gate ----------------
__global__ __launch_bounds__(256) void k_final(float* __restrict__ out, const bf16* __restrict__ y,
                                               const float* __restrict__ sg) {
  size_t i = (size_t)blockIdx.x * 256 + threadIdx.x;
  int c = (int)(i % 192);
  size_t pix = i / 192;
  int b = (int)(pix >> 16);
  out[i] += __bfloat162float(y[i]) * sg[b * 192 + c];
}

extern "C" void kernel_launch(void* const* d_in, const int* in_sizes, int n_in,
                              void* d_out, int out_size, void* d_ws, size_t ws_size,
                              hipStream_t stream) {
  const float* x     = (const float*)d_in[0];
  const float* n1g   = (const float*)d_in[1];
  const float* n1b   = (const float*)d_in[2];
  const float* qkvw  = (const float*)d_in[3];
  const float* qkvb  = (const float*)d_in[4];
  const float* rpb   = (const float*)d_in[5];
  const float* projw = (const float*)d_in[6];
  const float* projb = (const float*)d_in[7];
  const float* n2g   = (const float*)d_in[8];
  const float* n2b   = (const float*)d_in[9];
  const float* w1    = (const float*)d_in[10];
  const float* b1    = (const float*)d_in[11];
  const float* w2    = (const float*)d_in[12];
  const float* b2    = (const float*)d_in[13];
  const float* c1w   = (const float*)d_in[14];
  const float* c1b   = (const float*)d_in[15];
  const float* c2w   = (const float*)d_in[16];
  const float* c2b   = (const float*)d_in[17];
  const float* c3w   = (const float*)d_in[18];
  const float* c3b   = (const float*)d_in[19];
  const float* sfc1  = (const float*)d_in[20];
  const float* sfc2  = (const float*)d_in[21];
  float* out = (float*)d_out;

  if (ws_size < WS_NEEDED) return;

  char* ws = (char*)d_ws;
  bf16*  ybf  = (bf16*)(ws + OFF_Y);
  float* t1   = (float*)(ws + OFF_T1);
  float* t2   = (float*)(ws + OFF_T2);
  float* s0   = (float*)(ws + OFF_S0);
  float* sg   = (float*)(ws + OFF_SG);
  bf16*  wqkv = (bf16*)(ws + OFF_WQKV);
  bf16*  wprj = (bf16*)(ws + OFF_WPRJ);
  bf16*  wfc1 = (bf16*)(ws + OFF_WFC1);
  bf16*  wfc2 = (bf16*)(ws + OFF_WFC2);
  bf16*  c1wb = (bf16*)(ws + OFF_C1WB);

  hipMemsetAsync(s0, 0, 384 * sizeof(float), stream);
  hipMemsetAsync((char*)c1wb + 24 * 192 * sizeof(bf16), 0, 8 * 192 * sizeof(bf16), stream);

  k_f2b<<<(110592 + 255) / 256, 256, 0, stream>>>(qkvw, wqkv, 110592);
  k_f2b<<<(36864 + 255) / 256, 256, 0, stream>>>(projw, wprj, 36864);
  k_f2b<<<(147456 + 255) / 256, 256, 0, stream>>>(w1, wfc1, 147456);
  k_f2b<<<(147456 + 255) / 256, 256, 0, stream>>>(w2, wfc2, 147456);
  k_f2b<<<(4608 + 255) / 256, 256, 0, stream>>>(c1w, c1wb, 4608);

  // fused attention + LN1 + LCE conv1 (t1), writes x1 into d_out
  k_attn2<<<2048, 256, 0, stream>>>(x, n1g, n1b, wqkv, qkvb, rpb, wprj, projb,
                                    c1wb, c1b, t1, out);
  // LCE tail
  k_lce2t<<<512, 256, 0, stream>>>(t1, c2w, c2b, t2);
  k_lce3<<<(NTOK * 192) / 256, 256, 0, stream>>>(t2, c3w, c3b, ybf);
  k_pool<<<2048, 192, 0, stream>>>(ybf, s0);
  k_se<<<2, 256, 0, stream>>>(s0, sfc1, sfc2, sg);
  // MLP in-place on d_out
  k_mlp_mfma<<<NTOK / 32, 256, 0, stream>>>(out, n2g, n2b, wfc1, b1, wfc2, b2);
  // final: out = x2 + y * gate
  k_final<<<(NTOK * 192) / 256, 256, 0, stream>>>(out, ybf, sg);
}

// Round 4
// 1313.726 us; speedup vs baseline: 1.1223x; 1.1223x over previous
//
#include <hip/hip_runtime.h>
#include <hip/hip_bf16.h>

using bf16 = __hip_bfloat16;
typedef __attribute__((ext_vector_type(8))) short short8;
typedef __attribute__((ext_vector_type(4))) float float4v;

constexpr int NTOK = 131072;  // 2*256*256

// ---------------- workspace layout (bytes) ----------------
constexpr size_t OFF_Y    = 0;           // bf16 [2][65536][192]  50,331,648
constexpr size_t OFF_T1   = 50331648;    // f32  [131072][24]     12,582,912
constexpr size_t OFF_T2   = 62914560;    // f32  [131072][24]     12,582,912
constexpr size_t OFF_S0   = 75497472;    // f32  [2][192]
constexpr size_t OFF_SG   = 75499008;    // f32  [2][192]
constexpr size_t OFF_WQKV = 75500544;    // bf16 [576][192]       221,184
constexpr size_t OFF_WPRJ = 75721728;    // bf16 [192][192]        73,728
constexpr size_t OFF_WFC1 = 75795456;    // bf16 [768][192]       294,912
constexpr size_t OFF_WFC2 = 76090368;    // bf16 [192][768]       294,912
constexpr size_t OFF_C1WB = 76385280;    // bf16 [32][192]         12,288 (rows 24..31 zero)
constexpr size_t WS_NEEDED = 76397568;

__device__ __forceinline__ int region256(int t) { return t < 248 ? 0 : (t < 252 ? 1 : 2); }

__device__ __forceinline__ short8 lds8(const bf16* p) {
  return *reinterpret_cast<const short8*>(p);
}
__device__ __forceinline__ short8 glb8(const bf16* p) {
  return *reinterpret_cast<const short8*>(p);
}

// ---------------- fp32 -> bf16 weight convert ----------------
__global__ __launch_bounds__(256) void k_f2b(const float* __restrict__ s, bf16* __restrict__ d, int n) {
  int i = blockIdx.x * 256 + threadIdx.x;
  if (i < n) d[i] = __float2bfloat16(s[i]);
}

// ---------------- LCE conv3x3 24->24, LDS-tiled ----------------
__global__ __launch_bounds__(256) void k_lce2t(const float* __restrict__ t1, const float* __restrict__ w,
                                               const float* __restrict__ bia, float* __restrict__ t2) {
  __shared__ float halo[18 * 18 * 25];
  __shared__ float wlds[5184];
  int bid = blockIdx.x;  // 512 = 2 * 16 * 16
  int b = bid >> 8;
  int rem = bid & 255;
  int ty0 = ((rem >> 4) & 15) * 16, tx0 = (rem & 15) * 16;
  for (int idx = threadIdx.x; idx < 5184; idx += 256) wlds[idx] = w[idx];
  for (int idx = threadIdx.x; idx < 18 * 18 * 24; idx += 256) {
    int ch = idx % 24;
    int pp = idx / 24;
    int hy = pp / 18, hx = pp - hy * 18;
    int gy = ty0 + hy - 1, gx = tx0 + hx - 1;
    float v = 0.f;
    if (gy >= 0 && gy < 256 && gx >= 0 && gx < 256)
      v = t1[((size_t)(b << 16) + (gy << 8) + gx) * 24 + ch];
    halo[pp * 25 + ch] = v;
  }
  __syncthreads();
  int py = threadIdx.x >> 4, px = threadIdx.x & 15;
  float acc[24];
#pragma unroll
  for (int ro = 0; ro < 24; ++ro) acc[ro] = bia[ro];
  for (int ky = 0; ky < 3; ++ky) {
    for (int kx = 0; kx < 3; ++kx) {
      int base = ((py + ky) * 18 + px + kx) * 25;
      float inb[24];
#pragma unroll
      for (int ri = 0; ri < 24; ++ri) inb[ri] = halo[base + ri];
      int wo = ky * 3 + kx;
#pragma unroll
      for (int ro = 0; ro < 24; ++ro) {
        float a = acc[ro];
#pragma unroll
        for (int ri = 0; ri < 24; ++ri) a += inb[ri] * wlds[ro * 216 + ri * 9 + wo];
        acc[ro] = a;
      }
    }
  }
  size_t pix = (size_t)(b << 16) + ((ty0 + py) << 8) + tx0 + px;
#pragma unroll
  for (int ro = 0; ro < 24; ++ro) t2[pix * 24 + ro] = acc[ro];
}

// ---------------- LCE conv1x1 24->192 + LeakyReLU -> y (bf16) ----------------
__global__ __launch_bounds__(256) void k_lce3(const float* __restrict__ t2, const float* __restrict__ w,
                                              const float* __restrict__ bia, bf16* __restrict__ y) {
  size_t tid = (size_t)blockIdx.x * 256 + threadIdx.x;
  int c = (int)(tid % 192);
  size_t pix = tid / 192;
  const float* ir = t2 + pix * 24;
  const float* wr = w + c * 24;
  float acc = bia[c];
  for (int ri = 0; ri < 24; ++ri) acc += ir[ri] * wr[ri];
  if (acc < 0.f) acc *= 0.2f;
  y[tid] = __float2bfloat16(acc);
}

// ---------------- global avg pool partial sums ----------------
__global__ __launch_bounds__(192) void k_pool(const bf16* __restrict__ y, float* __restrict__ s0) {
  int b = blockIdx.x >> 10;
  int chunk = blockIdx.x & 1023;
  int c = threadIdx.x;
  size_t base = ((size_t)b * 65536 + chunk * 64) * 192;
  float acc = 0.f;
  for (int p = 0; p < 64; ++p) acc += __bfloat162float(y[base + (size_t)p * 192 + c]);
  atomicAdd(&s0[b * 192 + c], acc);
}

// ---------------- SE gate ----------------
__global__ __launch_bounds__(256) void k_se(const float* __restrict__ s0, const float* __restrict__ w1,
                                            const float* __restrict__ w2, float* __restrict__ sg) {
  __shared__ float mean[192];
  __shared__ float t[24];
  int b = blockIdx.x;
  int tid = threadIdx.x;
  if (tid < 192) mean[tid] = s0[b * 192 + tid] * (1.f / 65536.f);
  __syncthreads();
  if (tid < 24) {
    float a = 0.f;
    for (int c = 0; c < 192; ++c) a += mean[c] * w1[tid * 192 + c];
    t[tid] = fmaxf(a, 0.f);
  }
  __syncthreads();
  if (tid < 192) {
    float a = 0.f;
    for (int r = 0; r < 24; ++r) a += t[r] * w2[tid * 24 + r];
    sg[b * 192 + tid] = 1.f / (1.f + expf(-a));
  }
}

// ---------------- chunked fused attention (+ LCE conv1) ----------------
// 2048 blocks (one per window), 256 threads, wave w owns rows 16w..16w+15.
// R3 lesson: 4 blocks/CU at VGPR-cap 128 spilled projacc (FETCH/WRITE 3x).
// R4: 3 blocks/CU, zero-spill. K/V head-chunked (3 chunks x 2 heads), but O
// kept FULL-width in LDS (doubles as LN staging) and proj done once at the
// end -> no long-lived register accumulator. LDS = 49,152 B -> 3 blocks/CU;
// __launch_bounds__(256,3) -> VGPR cap ~170, live set ~100 -> no spill.
// All regions XOR-swizzled (byte ^= (row&7)<<4): 2-way-max b128 reads.
// Regions:
//   O   @0      [64][192] bf16 stride 384 (LN staging, then O; wave-private rows)
//   KL3 @24576  [64 tok][64 ch] bf16
//   VT3 @32768  [64 ch][64 tok] bf16
//   PS3 @40960  [64][64]  bf16 (per-wave Q/P scratch)
__device__ __forceinline__ int stg_b(int r, int c) { return (r * 384 + c * 2) ^ ((r & 7) << 4); }
__device__ __forceinline__ int kl3_b(int r, int c) { return 24576 + ((r * 128 + c * 2) ^ ((r & 7) << 4)); }
__device__ __forceinline__ int vt3_b(int r, int c) { return 32768 + ((r * 128 + c * 2) ^ ((r & 7) << 4)); }
__device__ __forceinline__ int ps3_b(int r, int c) { return 40960 + ((r * 128 + c * 2) ^ ((r & 7) << 4)); }

__device__ __forceinline__ short8 lds8o(const char* sm, int byteoff) {
  return *reinterpret_cast<const short8*>(sm + byteoff);
}
__device__ __forceinline__ void st16(char* sm, int byteoff, bf16 v) {
  *reinterpret_cast<bf16*>(sm + byteoff) = v;
}

__global__ __launch_bounds__(256, 3) void k_attn2(const float* __restrict__ x, const float* __restrict__ g,
                                                  const float* __restrict__ bb, const bf16* __restrict__ wq,
                                                  const float* __restrict__ qkvb, const float* __restrict__ rpb,
                                                  const bf16* __restrict__ wp, const float* __restrict__ projb,
                                                  const bf16* __restrict__ c1wb, const float* __restrict__ c1b,
                                                  float* __restrict__ t1, float* __restrict__ x1out) {
  __shared__ char sm[49152];

  int win = blockIdx.x;
  int b = win >> 10;
  int wrem = win & 1023;
  int wh = wrem >> 5, ww = wrem & 31;
  int tid = threadIdx.x;
  int wave = tid >> 6, lane = tid & 63;
  int colB = lane & 15, grp = lane >> 4;
  const float scale = 0.17677669529663687f;  // 1/sqrt(32)

  // ---- Phase 1: LN over this wave's 16 tokens (gather with roll -4) -> staging (wave-private rows)
  for (int t = 0; t < 16; ++t) {
    int tok = wave * 16 + t;
    int i = tok >> 3, j = tok & 7;
    int hp = (wh * 8 + i + 4) & 255;
    int wpp = (ww * 8 + j + 4) & 255;
    const float* xr = x + (((size_t)b << 16) + (hp << 8) + wpp) * 192;
    float v0 = xr[lane], v1 = xr[lane + 64], v2 = xr[lane + 128];
    float s = v0 + v1 + v2;
    for (int o = 32; o > 0; o >>= 1) s += __shfl_down(s, o);
    s = __shfl(s, 0);
    float m = s * (1.f / 192.f);
    float d0 = v0 - m, d1 = v1 - m, d2 = v2 - m;
    float q = d0 * d0 + d1 * d1 + d2 * d2;
    for (int o = 32; o > 0; o >>= 1) q += __shfl_down(q, o);
    q = __shfl(q, 0);
    float inv = rsqrtf(q * (1.f / 192.f) + 1e-5f);
    st16(sm, stg_b(tok, lane),       __float2bfloat16(d0 * inv * g[lane]       + bb[lane]));
    st16(sm, stg_b(tok, lane + 64),  __float2bfloat16(d1 * inv * g[lane + 64]  + bb[lane + 64]));
    st16(sm, stg_b(tok, lane + 128), __float2bfloat16(d2 * inv * g[lane + 128] + bb[lane + 128]));
  }

  // A-fragments of LN rows (same-wave LDS write->read, DS pipe in-order; no barrier needed)
  short8 axw[6];
#pragma unroll
  for (int kk = 0; kk < 6; ++kk) axw[kk] = lds8o(sm, stg_b(wave * 16 + colB, kk * 32 + 8 * grp));

  // row constants for bias/mask
  int l1r[4], i1r[4], j1r[4];
#pragma unroll
  for (int r = 0; r < 4; ++r) {
    int n = wave * 16 + 4 * grp + r;
    i1r[r] = n >> 3; j1r[r] = n & 7;
    l1r[r] = region256(wh * 8 + i1r[r]) * 3 + region256(ww * 8 + j1r[r]);
  }

  for (int gch = 0; gch < 3; ++gch) {  // chunk = heads {2g, 2g+1} = qkv cols 64g..64g+63
    // ---- QKV GEMM for this chunk (B-fragments straight from global bf16 weights)
    float qreg[16];
    {  // Q
      float4v qa[4] = {{0,0,0,0},{0,0,0,0},{0,0,0,0},{0,0,0,0}};
#pragma unroll
      for (int kk = 0; kk < 6; ++kk) {
#pragma unroll
        for (int jt = 0; jt < 4; ++jt) {
          int wrow = gch * 64 + jt * 16 + colB;
          qa[jt] = __builtin_amdgcn_mfma_f32_16x16x32_bf16(axw[kk], glb8(wq + (size_t)wrow * 192 + kk * 32 + 8 * grp), qa[jt], 0, 0, 0);
        }
      }
#pragma unroll
      for (int jt = 0; jt < 4; ++jt) {
        float bias = qkvb[gch * 64 + jt * 16 + colB];
#pragma unroll
        for (int r = 0; r < 4; ++r) qreg[jt * 4 + r] = (qa[jt][r] + bias) * scale;
      }
    }
    {  // K -> KL3 (rows = own tokens)
      float4v ka[4] = {{0,0,0,0},{0,0,0,0},{0,0,0,0},{0,0,0,0}};
#pragma unroll
      for (int kk = 0; kk < 6; ++kk) {
#pragma unroll
        for (int jt = 0; jt < 4; ++jt) {
          int wrow = 192 + gch * 64 + jt * 16 + colB;
          ka[jt] = __builtin_amdgcn_mfma_f32_16x16x32_bf16(axw[kk], glb8(wq + (size_t)wrow * 192 + kk * 32 + 8 * grp), ka[jt], 0, 0, 0);
        }
      }
#pragma unroll
      for (int jt = 0; jt < 4; ++jt) {
        float bias = qkvb[192 + gch * 64 + jt * 16 + colB];
#pragma unroll
        for (int r = 0; r < 4; ++r)
          st16(sm, kl3_b(wave * 16 + 4 * grp + r, jt * 16 + colB), __float2bfloat16(ka[jt][r] + bias));
      }
    }
    {  // V -> VT3 (transposed: rows = local channel, cols = own tokens)
      float4v va[4] = {{0,0,0,0},{0,0,0,0},{0,0,0,0},{0,0,0,0}};
#pragma unroll
      for (int kk = 0; kk < 6; ++kk) {
#pragma unroll
        for (int jt = 0; jt < 4; ++jt) {
          int wrow = 384 + gch * 64 + jt * 16 + colB;
          va[jt] = __builtin_amdgcn_mfma_f32_16x16x32_bf16(axw[kk], glb8(wq + (size_t)wrow * 192 + kk * 32 + 8 * grp), va[jt], 0, 0, 0);
        }
      }
#pragma unroll
      for (int jt = 0; jt < 4; ++jt) {
        float bias = qkvb[384 + gch * 64 + jt * 16 + colB];
#pragma unroll
        for (int r = 0; r < 4; ++r)
          st16(sm, vt3_b(jt * 16 + colB, wave * 16 + 4 * grp + r), __float2bfloat16(va[jt][r] + bias));
      }
    }
    if (gch == 0) {  // conv1 (LCE): 2 N-tiles, weights zero-padded to 32 rows
      float4v acc[2] = {{0,0,0,0},{0,0,0,0}};
#pragma unroll
      for (int kk = 0; kk < 6; ++kk) {
#pragma unroll
        for (int j = 0; j < 2; ++j) {
          int row = j * 16 + colB;
          acc[j] = __builtin_amdgcn_mfma_f32_16x16x32_bf16(axw[kk], glb8(c1wb + (size_t)row * 192 + kk * 32 + 8 * grp), acc[j], 0, 0, 0);
        }
      }
#pragma unroll
      for (int j = 0; j < 2; ++j) {
        int ch = j * 16 + colB;
        if (ch < 24) {
          float bias = c1b[ch];
#pragma unroll
          for (int r = 0; r < 4; ++r) {
            int tok = wave * 16 + 4 * grp + r;
            int i = tok >> 3, jj = tok & 7;
            int hp = (wh * 8 + i + 4) & 255;
            int wpp = (ww * 8 + jj + 4) & 255;
            size_t pix = ((size_t)b << 16) + (hp << 8) + wpp;
            t1[pix * 24 + ch] = acc[j][r] + bias;
          }
        }
      }
    }
    __syncthreads();  // K/V of this chunk visible to all waves

    // ---- attention for the chunk's 2 heads (PS3/O per-wave private)
#pragma unroll
    for (int hh = 0; hh < 2; ++hh) {
      int h = 2 * gch + hh;
      // Q tile -> scratch -> A-frag
#pragma unroll
      for (int t = 0; t < 2; ++t)
#pragma unroll
        for (int r = 0; r < 4; ++r)
          st16(sm, ps3_b(wave * 16 + 4 * grp + r, t * 16 + colB), __float2bfloat16(qreg[(hh * 2 + t) * 4 + r]));
      short8 aq = lds8o(sm, ps3_b(wave * 16 + colB, 8 * grp));

      float4v s[4];
#pragma unroll
      for (int nt = 0; nt < 4; ++nt) {
        short8 bk = lds8o(sm, kl3_b(nt * 16 + colB, hh * 32 + 8 * grp));
        float4v z = {0, 0, 0, 0};
        s[nt] = __builtin_amdgcn_mfma_f32_16x16x32_bf16(aq, bk, z, 0, 0, 0);
      }
#pragma unroll
      for (int nt = 0; nt < 4; ++nt) {
        int m = nt * 16 + colB;
        int i2 = m >> 3, j2 = m & 7;
        int l2 = region256(wh * 8 + i2) * 3 + region256(ww * 8 + j2);
#pragma unroll
        for (int r = 0; r < 4; ++r) {
          float bias = rpb[((i1r[r] - i2 + 7) * 15 + (j1r[r] - j2 + 7)) * 6 + h];
          s[nt][r] += bias + (l1r[r] != l2 ? -100.f : 0.f);
        }
      }
#pragma unroll
      for (int r = 0; r < 4; ++r) {
        float mx = fmaxf(fmaxf(s[0][r], s[1][r]), fmaxf(s[2][r], s[3][r]));
        mx = fmaxf(mx, __shfl_xor(mx, 1));
        mx = fmaxf(mx, __shfl_xor(mx, 2));
        mx = fmaxf(mx, __shfl_xor(mx, 4));
        mx = fmaxf(mx, __shfl_xor(mx, 8));
        float e0 = __expf(s[0][r] - mx), e1 = __expf(s[1][r] - mx);
        float e2 = __expf(s[2][r] - mx), e3 = __expf(s[3][r] - mx);
        float sum = e0 + e1 + e2 + e3;
        sum += __shfl_xor(sum, 1);
        sum += __shfl_xor(sum, 2);
        sum += __shfl_xor(sum, 4);
        sum += __shfl_xor(sum, 8);
        float inv = 1.f / sum;
        int row = wave * 16 + 4 * grp + r;
        st16(sm, ps3_b(row, 0 * 16 + colB), __float2bfloat16(e0 * inv));
        st16(sm, ps3_b(row, 1 * 16 + colB), __float2bfloat16(e1 * inv));
        st16(sm, ps3_b(row, 2 * 16 + colB), __float2bfloat16(e2 * inv));
        st16(sm, ps3_b(row, 3 * 16 + colB), __float2bfloat16(e3 * inv));
      }
      short8 ap0 = lds8o(sm, ps3_b(wave * 16 + colB, 0 * 32 + 8 * grp));
      short8 ap1 = lds8o(sm, ps3_b(wave * 16 + colB, 1 * 32 + 8 * grp));

      float4v o0 = {0, 0, 0, 0}, o1 = {0, 0, 0, 0};
      o0 = __builtin_amdgcn_mfma_f32_16x16x32_bf16(ap0, lds8o(sm, vt3_b(hh * 32 + colB, 8 * grp)), o0, 0, 0, 0);
      o0 = __builtin_amdgcn_mfma_f32_16x16x32_bf16(ap1, lds8o(sm, vt3_b(hh * 32 + colB, 32 + 8 * grp)), o0, 0, 0, 0);
      o1 = __builtin_amdgcn_mfma_f32_16x16x32_bf16(ap0, lds8o(sm, vt3_b(hh * 32 + 16 + colB, 8 * grp)), o1, 0, 0, 0);
      o1 = __builtin_amdgcn_mfma_f32_16x16x32_bf16(ap1, lds8o(sm, vt3_b(hh * 32 + 16 + colB, 32 + 8 * grp)), o1, 0, 0, 0);
      int ocol = gch * 64 + hh * 32;
#pragma unroll
      for (int r = 0; r < 4; ++r) {
        int row = wave * 16 + 4 * grp + r;
        st16(sm, stg_b(row, ocol + colB),      __float2bfloat16(o0[r]));  // O into staging region
        st16(sm, stg_b(row, ocol + 16 + colB), __float2bfloat16(o1[r]));
      }
    }
    if (gch != 2) __syncthreads();  // all waves done reading K/V before next chunk overwrites
  }

  // ---- Phase 4: proj + reverse-shift scatter + residual (O rows are wave-private)
  short8 ao[6];
#pragma unroll
  for (int kk = 0; kk < 6; ++kk) ao[kk] = lds8o(sm, stg_b(wave * 16 + colB, kk * 32 + 8 * grp));
  for (int gp = 0; gp < 4; ++gp) {
    float4v acc[3] = {{0,0,0,0},{0,0,0,0},{0,0,0,0}};
#pragma unroll
    for (int kk = 0; kk < 6; ++kk) {
#pragma unroll
      for (int j = 0; j < 3; ++j) {
        int col = (gp * 3 + j) * 16 + colB;
        acc[j] = __builtin_amdgcn_mfma_f32_16x16x32_bf16(ao[kk], glb8(wp + (size_t)col * 192 + kk * 32 + 8 * grp), acc[j], 0, 0, 0);
      }
    }
#pragma unroll
    for (int j = 0; j < 3; ++j) {
      int col = (gp * 3 + j) * 16 + colB;
      float bias = projb[col];
#pragma unroll
      for (int r = 0; r < 4; ++r) {
        int n = wave * 16 + 4 * grp + r;
        int i = n >> 3, jj = n & 7;
        int hd2 = (wh * 8 + i + 4) & 255;
        int wd2 = (ww * 8 + jj + 4) & 255;
        size_t p = (((size_t)b << 16) + (hd2 << 8) + wd2) * 192 + col;
        x1out[p] = x[p] + acc[j][r] + bias;
      }
    }
  }
}

// ---------------- MFMA MLP: LN2 + fc1 + GELU + fc2 + residual (in-place) ----------------
// Split fc1/fc2 into two 384-col halves (fc2 partials in regs) + XOR swizzle:
// LDS 36,864 B. __launch_bounds__(256,3): VGPR cap ~170 vs live ~100 -> no
// spill (R3's (256,4) cap-128 risked spilling a1f+d0a/d1a); 3 blocks/CU.
__device__ __forceinline__ int xl_b(int r, int c) { return (r * 384 + c * 2) ^ ((r & 7) << 4); }
__device__ __forceinline__ int hh_b(int r, int c) { return 12288 + ((r * 768 + c * 2) ^ ((r & 7) << 4)); }

__global__ __launch_bounds__(256, 3) void k_mlp_mfma(float* __restrict__ x1, const float* __restrict__ g,
                                                     const float* __restrict__ bb, const bf16* __restrict__ w1,
                                                     const float* __restrict__ b1, const bf16* __restrict__ w2,
                                                     const float* __restrict__ b2) {
  __shared__ char sm[36864];
  int tid = threadIdx.x;
  int wave = tid >> 6, lane = tid & 63;
  int colB = lane & 15, grp = lane >> 4;
  size_t tokbase = (size_t)blockIdx.x * 32;

  for (int t = wave; t < 32; t += 4) {
    const float* xr = x1 + (tokbase + t) * 192;
    float v0 = xr[lane], v1 = xr[lane + 64], v2 = xr[lane + 128];
    float s = v0 + v1 + v2;
    for (int o = 32; o > 0; o >>= 1) s += __shfl_down(s, o);
    s = __shfl(s, 0);
    float m = s * (1.f / 192.f);
    float d0 = v0 - m, d1 = v1 - m, d2 = v2 - m;
    float qq = d0 * d0 + d1 * d1 + d2 * d2;
    for (int o = 32; o > 0; o >>= 1) qq += __shfl_down(qq, o);
    qq = __shfl(qq, 0);
    float inv = rsqrtf(qq * (1.f / 192.f) + 1e-5f);
    st16(sm, xl_b(t, lane),       __float2bfloat16(d0 * inv * g[lane]       + bb[lane]));
    st16(sm, xl_b(t, lane + 64),  __float2bfloat16(d1 * inv * g[lane + 64]  + bb[lane + 64]));
    st16(sm, xl_b(t, lane + 128), __float2bfloat16(d2 * inv * g[lane + 128] + bb[lane + 128]));
  }
  __syncthreads();

  short8 a1f[6][2];
#pragma unroll
  for (int kk = 0; kk < 6; ++kk) {
    a1f[kk][0] = lds8o(sm, xl_b(colB, kk * 32 + 8 * grp));
    a1f[kk][1] = lds8o(sm, xl_b(16 + colB, kk * 32 + 8 * grp));
  }

  float4v d0a[3] = {{0,0,0,0},{0,0,0,0},{0,0,0,0}};
  float4v d1a[3] = {{0,0,0,0},{0,0,0,0},{0,0,0,0}};
  int ntb = wave * 3;

  for (int ph = 0; ph < 2; ++ph) {
    if (ph) __syncthreads();  // prior fc2 reads of hh complete before overwrite
    // fc1 half: 24 local tiles (384 cols), 6 per wave
    for (int nn = 0; nn < 6; ++nn) {
      int ntl = wave * 6 + nn;                 // local tile 0..23
      int colg = ph * 384 + ntl * 16 + colB;   // global fc1 col
      float4v c0 = {0, 0, 0, 0}, c1 = {0, 0, 0, 0};
#pragma unroll
      for (int kk = 0; kk < 6; ++kk) {
        short8 bw = glb8(w1 + (size_t)colg * 192 + kk * 32 + 8 * grp);
        c0 = __builtin_amdgcn_mfma_f32_16x16x32_bf16(a1f[kk][0], bw, c0, 0, 0, 0);
        c1 = __builtin_amdgcn_mfma_f32_16x16x32_bf16(a1f[kk][1], bw, c1, 0, 0, 0);
      }
      float bias = b1[colg];
      int coll = ntl * 16 + colB;
#pragma unroll
      for (int r = 0; r < 4; ++r) {
        float v0 = c0[r] + bias;
        float v1 = c1[r] + bias;
        v0 = v0 * 0.5f * (1.f + erff(v0 * 0.70710678118654752f));
        v1 = v1 * 0.5f * (1.f + erff(v1 * 0.70710678118654752f));
        st16(sm, hh_b(4 * grp + r, coll), __float2bfloat16(v0));
        st16(sm, hh_b(16 + 4 * grp + r, coll), __float2bfloat16(v1));
      }
    }
    __syncthreads();
    // fc2 partial over this half's 384 K
    for (int kk = 0; kk < 12; ++kk) {
      int kol = kk * 32 + 8 * grp;
      int kog = ph * 384 + kol;
      short8 h0 = lds8o(sm, hh_b(colB, kol));
      short8 h1 = lds8o(sm, hh_b(16 + colB, kol));
#pragma unroll
      for (int j = 0; j < 3; ++j) {
        short8 bw = glb8(w2 + (size_t)((ntb + j) * 16 + colB) * 768 + kog);
        d0a[j] = __builtin_amdgcn_mfma_f32_16x16x32_bf16(h0, bw, d0a[j], 0, 0, 0);
        d1a[j] = __builtin_amdgcn_mfma_f32_16x16x32_bf16(h1, bw, d1a[j], 0, 0, 0);
      }
    }
  }

#pragma unroll
  for (int j = 0; j < 3; ++j) {
    int col = (ntb + j) * 16 + colB;
    float bias = b2[col];
#pragma unroll
    for (int r = 0; r < 4; ++r) {
      size_t p0 = (tokbase + 4 * grp + r) * 192 + col;
      size_t p1 = (tokbase + 16 + 4 * grp + r) * 192 + col;
      x1[p0] += d0a[j][r] + bias;
      x1[p1] += d1a[j][r] + bias;
    }
  }
}

// ---------------- out += y * gate ----------------
__global__ __launch_bounds__(256) void k_final(float* __restrict__ out, const bf16* __restrict__ y,
                                               const float* __restrict__ sg) {
  size_t i = (size_t)blockIdx.x * 256 + threadIdx.x;
  int c = (int)(i % 192);
  size_t pix = i / 192;
  int b = (int)(pix >> 16);
  out[i] += __bfloat162float(y[i]) * sg[b * 192 + c];
}

extern "C" void kernel_launch(void* const* d_in, const int* in_sizes, int n_in,
                              void* d_out, int out_size, void* d_ws, size_t ws_size,
                              hipStream_t stream) {
  const float* x     = (const float*)d_in[0];
  const float* n1g   = (const float*)d_in[1];
  const float* n1b   = (const float*)d_in[2];
  const float* qkvw  = (const float*)d_in[3];
  const float* qkvb  = (const float*)d_in[4];
  const float* rpb   = (const float*)d_in[5];
  const float* projw = (const float*)d_in[6];
  const float* projb = (const float*)d_in[7];
  const float* n2g   = (const float*)d_in[8];
  const float* n2b   = (const float*)d_in[9];
  const float* w1    = (const float*)d_in[10];
  const float* b1    = (const float*)d_in[11];
  const float* w2    = (const float*)d_in[12];
  const float* b2    = (const float*)d_in[13];
  const float* c1w   = (const float*)d_in[14];
  const float* c1b   = (const float*)d_in[15];
  const float* c2w   = (const float*)d_in[16];
  const float* c2b   = (const float*)d_in[17];
  const float* c3w   = (const float*)d_in[18];
  const float* c3b   = (const float*)d_in[19];
  const float* sfc1  = (const float*)d_in[20];
  const float* sfc2  = (const float*)d_in[21];
  float* out = (float*)d_out;

  if (ws_size < WS_NEEDED) return;

  char* ws = (char*)d_ws;
  bf16*  ybf  = (bf16*)(ws + OFF_Y);
  float* t1   = (float*)(ws + OFF_T1);
  float* t2   = (float*)(ws + OFF_T2);
  float* s0   = (float*)(ws + OFF_S0);
  float* sg   = (float*)(ws + OFF_SG);
  bf16*  wqkv = (bf16*)(ws + OFF_WQKV);
  bf16*  wprj = (bf16*)(ws + OFF_WPRJ);
  bf16*  wfc1 = (bf16*)(ws + OFF_WFC1);
  bf16*  wfc2 = (bf16*)(ws + OFF_WFC2);
  bf16*  c1wb = (bf16*)(ws + OFF_C1WB);

  hipMemsetAsync(s0, 0, 384 * sizeof(float), stream);
  hipMemsetAsync((char*)c1wb + 24 * 192 * sizeof(bf16), 0, 8 * 192 * sizeof(bf16), stream);

  k_f2b<<<(110592 + 255) / 256, 256, 0, stream>>>(qkvw, wqkv, 110592);
  k_f2b<<<(36864 + 255) / 256, 256, 0, stream>>>(projw, wprj, 36864);
  k_f2b<<<(147456 + 255) / 256, 256, 0, stream>>>(w1, wfc1, 147456);
  k_f2b<<<(147456 + 255) / 256, 256, 0, stream>>>(w2, wfc2, 147456);
  k_f2b<<<(4608 + 255) / 256, 256, 0, stream>>>(c1w, c1wb, 4608);

  // fused attention + LN1 + LCE conv1 (t1), writes x1 into d_out
  k_attn2<<<2048, 256, 0, stream>>>(x, n1g, n1b, wqkv, qkvb, rpb, wprj, projb,
                                    c1wb, c1b, t1, out);
  // LCE tail
  k_lce2t<<<512, 256, 0, stream>>>(t1, c2w, c2b, t2);
  k_lce3<<<(NTOK * 192) / 256, 256, 0, stream>>>(t2, c3w, c3b, ybf);
  k_pool<<<2048, 192, 0, stream>>>(ybf, s0);
  k_se<<<2, 256, 0, stream>>>(s0, sfc1, sfc2, sg);
  // MLP in-place on d_out
  k_mlp_mfma<<<NTOK / 32, 256, 0, stream>>>(out, n2g, n2b, wfc1, b1, wfc2, b2);
  // final: out = x2 + y * gate
  k_final<<<(NTOK * 192) / 256, 256, 0, stream>>>(out, ybf, sg);
}

// Round 5
// 1103.502 us; speedup vs baseline: 1.3361x; 1.1905x over previous
//
#include <hip/hip_runtime.h>
#include <hip/hip_bf16.h>

using bf16 = __hip_bfloat16;
typedef __attribute__((ext_vector_type(8))) short short8;
typedef __attribute__((ext_vector_type(4))) float float4v;

constexpr int NTOK = 131072;  // 2*256*256

// ---------------- workspace layout (bytes) ----------------
constexpr size_t OFF_Y    = 0;           // bf16 [2][65536][192]  50,331,648
constexpr size_t OFF_T1   = 50331648;    // f32  [131072][24]     12,582,912
constexpr size_t OFF_T2   = 62914560;    // f32  [131072][24]     12,582,912
constexpr size_t OFF_S0   = 75497472;    // f32  [2][192]
constexpr size_t OFF_SG   = 75499008;    // f32  [2][192]  (unused now)
constexpr size_t OFF_WQKV = 75500544;    // bf16 [576][192]       221,184
constexpr size_t OFF_WPRJ = 75721728;    // bf16 [192][192]        73,728
constexpr size_t OFF_WFC1 = 75795456;    // bf16 [768][192]       294,912
constexpr size_t OFF_WFC2 = 76090368;    // bf16 [192][768]       294,912
constexpr size_t OFF_C1WB = 76385280;    // bf16 [32][192]         12,288 (rows 24..31 zero)
constexpr size_t WS_NEEDED = 76397568;

__device__ __forceinline__ int region256(int t) { return t < 248 ? 0 : (t < 252 ? 1 : 2); }

__device__ __forceinline__ short8 lds8(const bf16* p) {
  return *reinterpret_cast<const short8*>(p);
}
__device__ __forceinline__ short8 glb8(const bf16* p) {
  return *reinterpret_cast<const short8*>(p);
}

// ---------------- fp32 -> bf16 weight convert (all 5 tensors, one dispatch) ----------------
__global__ __launch_bounds__(256) void k_f2b_all(const float* __restrict__ qkvw, const float* __restrict__ projw,
                                                 const float* __restrict__ w1, const float* __restrict__ w2,
                                                 const float* __restrict__ c1w,
                                                 bf16* __restrict__ wqkv, bf16* __restrict__ wprj,
                                                 bf16* __restrict__ wfc1, bf16* __restrict__ wfc2,
                                                 bf16* __restrict__ c1wb) {
  int i = blockIdx.x * 256 + threadIdx.x;
  if (i < 110592) { wqkv[i] = __float2bfloat16(qkvw[i]); return; }
  i -= 110592;
  if (i < 36864) { wprj[i] = __float2bfloat16(projw[i]); return; }
  i -= 36864;
  if (i < 147456) { wfc1[i] = __float2bfloat16(w1[i]); return; }
  i -= 147456;
  if (i < 147456) { wfc2[i] = __float2bfloat16(w2[i]); return; }
  i -= 147456;
  if (i < 4608) c1wb[i] = __float2bfloat16(c1w[i]);
}

// ---------------- chunked fused attention (+ LCE conv1) — unchanged from R4 ----------------
__device__ __forceinline__ int stg_b(int r, int c) { return (r * 384 + c * 2) ^ ((r & 7) << 4); }
__device__ __forceinline__ int kl3_b(int r, int c) { return 24576 + ((r * 128 + c * 2) ^ ((r & 7) << 4)); }
__device__ __forceinline__ int vt3_b(int r, int c) { return 32768 + ((r * 128 + c * 2) ^ ((r & 7) << 4)); }
__device__ __forceinline__ int ps3_b(int r, int c) { return 40960 + ((r * 128 + c * 2) ^ ((r & 7) << 4)); }

__device__ __forceinline__ short8 lds8o(const char* sm, int byteoff) {
  return *reinterpret_cast<const short8*>(sm + byteoff);
}
__device__ __forceinline__ void st16(char* sm, int byteoff, bf16 v) {
  *reinterpret_cast<bf16*>(sm + byteoff) = v;
}

__global__ __launch_bounds__(256, 3) void k_attn2(const float* __restrict__ x, const float* __restrict__ g,
                                                  const float* __restrict__ bb, const bf16* __restrict__ wq,
                                                  const float* __restrict__ qkvb, const float* __restrict__ rpb,
                                                  const bf16* __restrict__ wp, const float* __restrict__ projb,
                                                  const bf16* __restrict__ c1wb, const float* __restrict__ c1b,
                                                  float* __restrict__ t1, float* __restrict__ x1out) {
  __shared__ char sm[49152];

  int win = blockIdx.x;
  int b = win >> 10;
  int wrem = win & 1023;
  int wh = wrem >> 5, ww = wrem & 31;
  int tid = threadIdx.x;
  int wave = tid >> 6, lane = tid & 63;
  int colB = lane & 15, grp = lane >> 4;
  const float scale = 0.17677669529663687f;  // 1/sqrt(32)

  // ---- Phase 1: LN over this wave's 16 tokens (gather with roll -4) -> staging (wave-private rows)
  for (int t = 0; t < 16; ++t) {
    int tok = wave * 16 + t;
    int i = tok >> 3, j = tok & 7;
    int hp = (wh * 8 + i + 4) & 255;
    int wpp = (ww * 8 + j + 4) & 255;
    const float* xr = x + (((size_t)b << 16) + (hp << 8) + wpp) * 192;
    float v0 = xr[lane], v1 = xr[lane + 64], v2 = xr[lane + 128];
    float s = v0 + v1 + v2;
    for (int o = 32; o > 0; o >>= 1) s += __shfl_down(s, o);
    s = __shfl(s, 0);
    float m = s * (1.f / 192.f);
    float d0 = v0 - m, d1 = v1 - m, d2 = v2 - m;
    float q = d0 * d0 + d1 * d1 + d2 * d2;
    for (int o = 32; o > 0; o >>= 1) q += __shfl_down(q, o);
    q = __shfl(q, 0);
    float inv = rsqrtf(q * (1.f / 192.f) + 1e-5f);
    st16(sm, stg_b(tok, lane),       __float2bfloat16(d0 * inv * g[lane]       + bb[lane]));
    st16(sm, stg_b(tok, lane + 64),  __float2bfloat16(d1 * inv * g[lane + 64]  + bb[lane + 64]));
    st16(sm, stg_b(tok, lane + 128), __float2bfloat16(d2 * inv * g[lane + 128] + bb[lane + 128]));
  }

  short8 axw[6];
#pragma unroll
  for (int kk = 0; kk < 6; ++kk) axw[kk] = lds8o(sm, stg_b(wave * 16 + colB, kk * 32 + 8 * grp));

  int l1r[4], i1r[4], j1r[4];
#pragma unroll
  for (int r = 0; r < 4; ++r) {
    int n = wave * 16 + 4 * grp + r;
    i1r[r] = n >> 3; j1r[r] = n & 7;
    l1r[r] = region256(wh * 8 + i1r[r]) * 3 + region256(ww * 8 + j1r[r]);
  }

  for (int gch = 0; gch < 3; ++gch) {  // chunk = heads {2g, 2g+1}
    float qreg[16];
    {  // Q
      float4v qa[4] = {{0,0,0,0},{0,0,0,0},{0,0,0,0},{0,0,0,0}};
#pragma unroll
      for (int kk = 0; kk < 6; ++kk) {
#pragma unroll
        for (int jt = 0; jt < 4; ++jt) {
          int wrow = gch * 64 + jt * 16 + colB;
          qa[jt] = __builtin_amdgcn_mfma_f32_16x16x32_bf16(axw[kk], glb8(wq + (size_t)wrow * 192 + kk * 32 + 8 * grp), qa[jt], 0, 0, 0);
        }
      }
#pragma unroll
      for (int jt = 0; jt < 4; ++jt) {
        float bias = qkvb[gch * 64 + jt * 16 + colB];
#pragma unroll
        for (int r = 0; r < 4; ++r) qreg[jt * 4 + r] = (qa[jt][r] + bias) * scale;
      }
    }
    {  // K -> KL3
      float4v ka[4] = {{0,0,0,0},{0,0,0,0},{0,0,0,0},{0,0,0,0}};
#pragma unroll
      for (int kk = 0; kk < 6; ++kk) {
#pragma unroll
        for (int jt = 0; jt < 4; ++jt) {
          int wrow = 192 + gch * 64 + jt * 16 + colB;
          ka[jt] = __builtin_amdgcn_mfma_f32_16x16x32_bf16(axw[kk], glb8(wq + (size_t)wrow * 192 + kk * 32 + 8 * grp), ka[jt], 0, 0, 0);
        }
      }
#pragma unroll
      for (int jt = 0; jt < 4; ++jt) {
        float bias = qkvb[192 + gch * 64 + jt * 16 + colB];
#pragma unroll
        for (int r = 0; r < 4; ++r)
          st16(sm, kl3_b(wave * 16 + 4 * grp + r, jt * 16 + colB), __float2bfloat16(ka[jt][r] + bias));
      }
    }
    {  // V -> VT3 (transposed)
      float4v va[4] = {{0,0,0,0},{0,0,0,0},{0,0,0,0},{0,0,0,0}};
#pragma unroll
      for (int kk = 0; kk < 6; ++kk) {
#pragma unroll
        for (int jt = 0; jt < 4; ++jt) {
          int wrow = 384 + gch * 64 + jt * 16 + colB;
          va[jt] = __builtin_amdgcn_mfma_f32_16x16x32_bf16(axw[kk], glb8(wq + (size_t)wrow * 192 + kk * 32 + 8 * grp), va[jt], 0, 0, 0);
        }
      }
#pragma unroll
      for (int jt = 0; jt < 4; ++jt) {
        float bias = qkvb[384 + gch * 64 + jt * 16 + colB];
#pragma unroll
        for (int r = 0; r < 4; ++r)
          st16(sm, vt3_b(jt * 16 + colB, wave * 16 + 4 * grp + r), __float2bfloat16(va[jt][r] + bias));
      }
    }
    if (gch == 0) {  // conv1 (LCE)
      float4v acc[2] = {{0,0,0,0},{0,0,0,0}};
#pragma unroll
      for (int kk = 0; kk < 6; ++kk) {
#pragma unroll
        for (int j = 0; j < 2; ++j) {
          int row = j * 16 + colB;
          acc[j] = __builtin_amdgcn_mfma_f32_16x16x32_bf16(axw[kk], glb8(c1wb + (size_t)row * 192 + kk * 32 + 8 * grp), acc[j], 0, 0, 0);
        }
      }
#pragma unroll
      for (int j = 0; j < 2; ++j) {
        int ch = j * 16 + colB;
        if (ch < 24) {
          float bias = c1b[ch];
#pragma unroll
          for (int r = 0; r < 4; ++r) {
            int tok = wave * 16 + 4 * grp + r;
            int i = tok >> 3, jj = tok & 7;
            int hp = (wh * 8 + i + 4) & 255;
            int wpp = (ww * 8 + jj + 4) & 255;
            size_t pix = ((size_t)b << 16) + (hp << 8) + wpp;
            t1[pix * 24 + ch] = acc[j][r] + bias;
          }
        }
      }
    }
    __syncthreads();

#pragma unroll
    for (int hh = 0; hh < 2; ++hh) {
      int h = 2 * gch + hh;
#pragma unroll
      for (int t = 0; t < 2; ++t)
#pragma unroll
        for (int r = 0; r < 4; ++r)
          st16(sm, ps3_b(wave * 16 + 4 * grp + r, t * 16 + colB), __float2bfloat16(qreg[(hh * 2 + t) * 4 + r]));
      short8 aq = lds8o(sm, ps3_b(wave * 16 + colB, 8 * grp));

      float4v s[4];
#pragma unroll
      for (int nt = 0; nt < 4; ++nt) {
        short8 bk = lds8o(sm, kl3_b(nt * 16 + colB, hh * 32 + 8 * grp));
        float4v z = {0, 0, 0, 0};
        s[nt] = __builtin_amdgcn_mfma_f32_16x16x32_bf16(aq, bk, z, 0, 0, 0);
      }
#pragma unroll
      for (int nt = 0; nt < 4; ++nt) {
        int m = nt * 16 + colB;
        int i2 = m >> 3, j2 = m & 7;
        int l2 = region256(wh * 8 + i2) * 3 + region256(ww * 8 + j2);
#pragma unroll
        for (int r = 0; r < 4; ++r) {
          float bias = rpb[((i1r[r] - i2 + 7) * 15 + (j1r[r] - j2 + 7)) * 6 + h];
          s[nt][r] += bias + (l1r[r] != l2 ? -100.f : 0.f);
        }
      }
#pragma unroll
      for (int r = 0; r < 4; ++r) {
        float mx = fmaxf(fmaxf(s[0][r], s[1][r]), fmaxf(s[2][r], s[3][r]));
        mx = fmaxf(mx, __shfl_xor(mx, 1));
        mx = fmaxf(mx, __shfl_xor(mx, 2));
        mx = fmaxf(mx, __shfl_xor(mx, 4));
        mx = fmaxf(mx, __shfl_xor(mx, 8));
        float e0 = __expf(s[0][r] - mx), e1 = __expf(s[1][r] - mx);
        float e2 = __expf(s[2][r] - mx), e3 = __expf(s[3][r] - mx);
        float sum = e0 + e1 + e2 + e3;
        sum += __shfl_xor(sum, 1);
        sum += __shfl_xor(sum, 2);
        sum += __shfl_xor(sum, 4);
        sum += __shfl_xor(sum, 8);
        float inv = 1.f / sum;
        int row = wave * 16 + 4 * grp + r;
        st16(sm, ps3_b(row, 0 * 16 + colB), __float2bfloat16(e0 * inv));
        st16(sm, ps3_b(row, 1 * 16 + colB), __float2bfloat16(e1 * inv));
        st16(sm, ps3_b(row, 2 * 16 + colB), __float2bfloat16(e2 * inv));
        st16(sm, ps3_b(row, 3 * 16 + colB), __float2bfloat16(e3 * inv));
      }
      short8 ap0 = lds8o(sm, ps3_b(wave * 16 + colB, 0 * 32 + 8 * grp));
      short8 ap1 = lds8o(sm, ps3_b(wave * 16 + colB, 1 * 32 + 8 * grp));

      float4v o0 = {0, 0, 0, 0}, o1 = {0, 0, 0, 0};
      o0 = __builtin_amdgcn_mfma_f32_16x16x32_bf16(ap0, lds8o(sm, vt3_b(hh * 32 + colB, 8 * grp)), o0, 0, 0, 0);
      o0 = __builtin_amdgcn_mfma_f32_16x16x32_bf16(ap1, lds8o(sm, vt3_b(hh * 32 + colB, 32 + 8 * grp)), o0, 0, 0, 0);
      o1 = __builtin_amdgcn_mfma_f32_16x16x32_bf16(ap0, lds8o(sm, vt3_b(hh * 32 + 16 + colB, 8 * grp)), o1, 0, 0, 0);
      o1 = __builtin_amdgcn_mfma_f32_16x16x32_bf16(ap1, lds8o(sm, vt3_b(hh * 32 + 16 + colB, 32 + 8 * grp)), o1, 0, 0, 0);
      int ocol = gch * 64 + hh * 32;
#pragma unroll
      for (int r = 0; r < 4; ++r) {
        int row = wave * 16 + 4 * grp + r;
        st16(sm, stg_b(row, ocol + colB),      __float2bfloat16(o0[r]));
        st16(sm, stg_b(row, ocol + 16 + colB), __float2bfloat16(o1[r]));
      }
    }
    if (gch != 2) __syncthreads();
  }

  // ---- Phase 4: proj + reverse-shift scatter + residual
  short8 ao[6];
#pragma unroll
  for (int kk = 0; kk < 6; ++kk) ao[kk] = lds8o(sm, stg_b(wave * 16 + colB, kk * 32 + 8 * grp));
  for (int gp = 0; gp < 4; ++gp) {
    float4v acc[3] = {{0,0,0,0},{0,0,0,0},{0,0,0,0}};
#pragma unroll
    for (int kk = 0; kk < 6; ++kk) {
#pragma unroll
      for (int j = 0; j < 3; ++j) {
        int col = (gp * 3 + j) * 16 + colB;
        acc[j] = __builtin_amdgcn_mfma_f32_16x16x32_bf16(ao[kk], glb8(wp + (size_t)col * 192 + kk * 32 + 8 * grp), acc[j], 0, 0, 0);
      }
    }
#pragma unroll
    for (int j = 0; j < 3; ++j) {
      int col = (gp * 3 + j) * 16 + colB;
      float bias = projb[col];
#pragma unroll
      for (int r = 0; r < 4; ++r) {
        int n = wave * 16 + 4 * grp + r;
        int i = n >> 3, jj = n & 7;
        int hd2 = (wh * 8 + i + 4) & 255;
        int wd2 = (ww * 8 + jj + 4) & 255;
        size_t p = (((size_t)b << 16) + (hd2 << 8) + wd2) * 192 + col;
        x1out[p] = x[p] + acc[j][r] + bias;
      }
    }
  }
}

// ---------------- FUSED: [LCE conv3x3 (512 blocks)] | [MFMA MLP (4096 blocks)] ----------------
// Independent after k_attn2 (lce2t reads t1; mlp reads/writes out). One dispatch
// of 4608 blocks hides lce2t's ~120us inside the MLP's occupancy gaps.
// MLP body = R1 known-good version (padded LDS, single fc1+fc2 pass, 2 blk/CU).
__global__ __launch_bounds__(256, 2) void k_mlp_lce2(float* __restrict__ x1, const float* __restrict__ g,
                                                     const float* __restrict__ bb, const bf16* __restrict__ w1,
                                                     const float* __restrict__ b1, const bf16* __restrict__ w2,
                                                     const float* __restrict__ b2,
                                                     const float* __restrict__ t1, const float* __restrict__ cw,
                                                     const float* __restrict__ cbia, float* __restrict__ t2) {
  __shared__ __align__(16) char smu[62464];
  int tid = threadIdx.x;

  if (blockIdx.x < 512) {
    // ---------- LCE conv3x3 24->24 ----------
    float* halo = (float*)smu;            // 18*18*25 floats = 32,400 B
    float* wlds = (float*)(smu + 32400);  // 5184 floats = 20,736 B
    int bid = blockIdx.x;
    int b = bid >> 8;
    int rem = bid & 255;
    int ty0 = ((rem >> 4) & 15) * 16, tx0 = (rem & 15) * 16;
    for (int idx = tid; idx < 5184; idx += 256) wlds[idx] = cw[idx];
    for (int idx = tid; idx < 18 * 18 * 24; idx += 256) {
      int ch = idx % 24;
      int pp = idx / 24;
      int hy = pp / 18, hx = pp - hy * 18;
      int gy = ty0 + hy - 1, gx = tx0 + hx - 1;
      float v = 0.f;
      if (gy >= 0 && gy < 256 && gx >= 0 && gx < 256)
        v = t1[((size_t)(b << 16) + (gy << 8) + gx) * 24 + ch];
      halo[pp * 25 + ch] = v;
    }
    __syncthreads();
    int py = tid >> 4, px = tid & 15;
    float acc[24];
#pragma unroll
    for (int ro = 0; ro < 24; ++ro) acc[ro] = cbia[ro];
    for (int ky = 0; ky < 3; ++ky) {
      for (int kx = 0; kx < 3; ++kx) {
        int base = ((py + ky) * 18 + px + kx) * 25;
        float inb[24];
#pragma unroll
        for (int ri = 0; ri < 24; ++ri) inb[ri] = halo[base + ri];
        int wo = ky * 3 + kx;
#pragma unroll
        for (int ro = 0; ro < 24; ++ro) {
          float a = acc[ro];
#pragma unroll
          for (int ri = 0; ri < 24; ++ri) a += inb[ri] * wlds[ro * 216 + ri * 9 + wo];
          acc[ro] = a;
        }
      }
    }
    size_t pix = (size_t)(b << 16) + ((ty0 + py) << 8) + tx0 + px;
#pragma unroll
    for (int ro = 0; ro < 24; ++ro) t2[pix * 24 + ro] = acc[ro];
    return;
  }

  // ---------- MFMA MLP: LN2 + fc1 + GELU + fc2 + residual (in-place) ----------
  bf16 (*xl)[200] = reinterpret_cast<bf16(*)[200]>(smu);            // 12,800 B
  bf16 (*hh)[776] = reinterpret_cast<bf16(*)[776]>(smu + 12800);    // 49,664 B
  int wave = tid >> 6, lane = tid & 63;
  int colB = lane & 15, grp = lane >> 4;
  size_t tokbase = (size_t)(blockIdx.x - 512) * 32;

  for (int t = wave; t < 32; t += 4) {
    const float* xr = x1 + (tokbase + t) * 192;
    float v0 = xr[lane], v1 = xr[lane + 64], v2 = xr[lane + 128];
    float s = v0 + v1 + v2;
    for (int o = 32; o > 0; o >>= 1) s += __shfl_down(s, o);
    s = __shfl(s, 0);
    float m = s * (1.f / 192.f);
    float d0 = v0 - m, d1 = v1 - m, d2 = v2 - m;
    float qq = d0 * d0 + d1 * d1 + d2 * d2;
    for (int o = 32; o > 0; o >>= 1) qq += __shfl_down(qq, o);
    qq = __shfl(qq, 0);
    float inv = rsqrtf(qq * (1.f / 192.f) + 1e-5f);
    xl[t][lane]       = __float2bfloat16(d0 * inv * g[lane]       + bb[lane]);
    xl[t][lane + 64]  = __float2bfloat16(d1 * inv * g[lane + 64]  + bb[lane + 64]);
    xl[t][lane + 128] = __float2bfloat16(d2 * inv * g[lane + 128] + bb[lane + 128]);
  }
  __syncthreads();

  short8 a1f[6][2];
#pragma unroll
  for (int kk = 0; kk < 6; ++kk) {
    a1f[kk][0] = lds8(&xl[colB][kk * 32 + 8 * grp]);
    a1f[kk][1] = lds8(&xl[16 + colB][kk * 32 + 8 * grp]);
  }
  for (int nn = 0; nn < 12; ++nn) {
    int nt = wave * 12 + nn;
    float4v c0 = {0, 0, 0, 0}, c1 = {0, 0, 0, 0};
#pragma unroll
    for (int kk = 0; kk < 6; ++kk) {
      short8 bw = glb8(w1 + (size_t)(nt * 16 + colB) * 192 + kk * 32 + 8 * grp);
      c0 = __builtin_amdgcn_mfma_f32_16x16x32_bf16(a1f[kk][0], bw, c0, 0, 0, 0);
      c1 = __builtin_amdgcn_mfma_f32_16x16x32_bf16(a1f[kk][1], bw, c1, 0, 0, 0);
    }
    int col = nt * 16 + colB;
    float bias = b1[col];
#pragma unroll
    for (int r = 0; r < 4; ++r) {
      float v0 = c0[r] + bias;
      float v1 = c1[r] + bias;
      v0 = v0 * 0.5f * (1.f + erff(v0 * 0.70710678118654752f));
      v1 = v1 * 0.5f * (1.f + erff(v1 * 0.70710678118654752f));
      hh[4 * grp + r][col] = __float2bfloat16(v0);
      hh[16 + 4 * grp + r][col] = __float2bfloat16(v1);
    }
  }
  __syncthreads();

  float4v d0[3] = {{0,0,0,0},{0,0,0,0},{0,0,0,0}};
  float4v d1[3] = {{0,0,0,0},{0,0,0,0},{0,0,0,0}};
  int ntb = wave * 3;
  for (int kk = 0; kk < 24; ++kk) {
    int ko = kk * 32 + 8 * grp;
    short8 h0 = lds8(&hh[colB][ko]);
    short8 h1 = lds8(&hh[16 + colB][ko]);
#pragma unroll
    for (int j = 0; j < 3; ++j) {
      short8 bw = glb8(w2 + (size_t)((ntb + j) * 16 + colB) * 768 + ko);
      d0[j] = __builtin_amdgcn_mfma_f32_16x16x32_bf16(h0, bw, d0[j], 0, 0, 0);
      d1[j] = __builtin_amdgcn_mfma_f32_16x16x32_bf16(h1, bw, d1[j], 0, 0, 0);
    }
  }
#pragma unroll
  for (int j = 0; j < 3; ++j) {
    int col = (ntb + j) * 16 + colB;
    float bias = b2[col];
#pragma unroll
    for (int r = 0; r < 4; ++r) {
      size_t p0 = (tokbase + 4 * grp + r) * 192 + col;
      size_t p1 = (tokbase + 16 + 4 * grp + r) * 192 + col;
      x1[p0] += d0[j][r] + bias;
      x1[p1] += d1[j][r] + bias;
    }
  }
}

// ---------------- FUSED: LCE conv1x1 24->192 + LeakyReLU + global-pool partials ----------------
// 2048 blocks x 192 threads; thread c handles channel c over 64 pixels; one
// atomicAdd per thread. Eliminates k_pool's 50 MB y re-read.
__global__ __launch_bounds__(192) void k_lce3p(const float* __restrict__ t2, const float* __restrict__ w,
                                               const float* __restrict__ bia, bf16* __restrict__ y,
                                               float* __restrict__ s0) {
  int b = blockIdx.x >> 10;
  int chunk = blockIdx.x & 1023;
  int c = threadIdx.x;
  float wr[24];
#pragma unroll
  for (int i = 0; i < 24; ++i) wr[i] = w[c * 24 + i];
  float bias = bia[c];
  float psum = 0.f;
  size_t pix0 = (size_t)b * 65536 + chunk * 64;
  for (int p = 0; p < 64; ++p) {
    const float* ir = t2 + (pix0 + p) * 24;
    float acc = bias;
#pragma unroll
    for (int i = 0; i < 24; ++i) acc += ir[i] * wr[i];
    if (acc < 0.f) acc *= 0.2f;
    y[(pix0 + p) * 192 + c] = __float2bfloat16(acc);
    psum += acc;
  }
  atomicAdd(&s0[b * 192 + c], psum);
}

// ---------------- FUSED: SE gate (recomputed per block) + out += y*gate ----------------
// 2048 blocks x 256 threads, 64 pixels each. SE = 9.2K MACs amortized over
// 12,288 elements. Eliminates k_se dispatch.
__global__ __launch_bounds__(256) void k_final2(float* __restrict__ out, const bf16* __restrict__ y,
                                                const float* __restrict__ s0, const float* __restrict__ w1se,
                                                const float* __restrict__ w2se) {
  __shared__ float mean[192];
  __shared__ float tt[24];
  __shared__ float sg[192];
  int b = blockIdx.x >> 10;
  int chunk = blockIdx.x & 1023;
  int tid = threadIdx.x;
  if (tid < 192) mean[tid] = s0[b * 192 + tid] * (1.f / 65536.f);
  __syncthreads();
  if (tid < 24) {
    float a = 0.f;
    for (int c = 0; c < 192; ++c) a += mean[c] * w1se[tid * 192 + c];
    tt[tid] = fmaxf(a, 0.f);
  }
  __syncthreads();
  if (tid < 192) {
    float a = 0.f;
    for (int r = 0; r < 24; ++r) a += tt[r] * w2se[tid * 24 + r];
    sg[tid] = 1.f / (1.f + expf(-a));
  }
  __syncthreads();
  size_t base = ((size_t)b * 65536 + chunk * 64) * 192;
  int c = tid >= 192 ? tid - 192 : tid;
  for (int it = 0; it < 48; ++it) {
    size_t e = base + (size_t)it * 256 + tid;
    out[e] += __bfloat162float(y[e]) * sg[c];
    c += 64;
    if (c >= 192) c -= 192;
  }
}

extern "C" void kernel_launch(void* const* d_in, const int* in_sizes, int n_in,
                              void* d_out, int out_size, void* d_ws, size_t ws_size,
                              hipStream_t stream) {
  const float* x     = (const float*)d_in[0];
  const float* n1g   = (const float*)d_in[1];
  const float* n1b   = (const float*)d_in[2];
  const float* qkvw  = (const float*)d_in[3];
  const float* qkvb  = (const float*)d_in[4];
  const float* rpb   = (const float*)d_in[5];
  const float* projw = (const float*)d_in[6];
  const float* projb = (const float*)d_in[7];
  const float* n2g   = (const float*)d_in[8];
  const float* n2b   = (const float*)d_in[9];
  const float* w1    = (const float*)d_in[10];
  const float* b1    = (const float*)d_in[11];
  const float* w2    = (const float*)d_in[12];
  const float* b2    = (const float*)d_in[13];
  const float* c1w   = (const float*)d_in[14];
  const float* c1b   = (const float*)d_in[15];
  const float* c2w   = (const float*)d_in[16];
  const float* c2b   = (const float*)d_in[17];
  const float* c3w   = (const float*)d_in[18];
  const float* c3b   = (const float*)d_in[19];
  const float* sfc1  = (const float*)d_in[20];
  const float* sfc2  = (const float*)d_in[21];
  float* out = (float*)d_out;

  if (ws_size < WS_NEEDED) return;

  char* ws = (char*)d_ws;
  bf16*  ybf  = (bf16*)(ws + OFF_Y);
  float* t1   = (float*)(ws + OFF_T1);
  float* t2   = (float*)(ws + OFF_T2);
  float* s0   = (float*)(ws + OFF_S0);
  bf16*  wqkv = (bf16*)(ws + OFF_WQKV);
  bf16*  wprj = (bf16*)(ws + OFF_WPRJ);
  bf16*  wfc1 = (bf16*)(ws + OFF_WFC1);
  bf16*  wfc2 = (bf16*)(ws + OFF_WFC2);
  bf16*  c1wb = (bf16*)(ws + OFF_C1WB);

  hipMemsetAsync(s0, 0, 384 * sizeof(float), stream);
  hipMemsetAsync((char*)c1wb + 24 * 192 * sizeof(bf16), 0, 8 * 192 * sizeof(bf16), stream);

  // all weight converts in one dispatch (446,976 elements)
  k_f2b_all<<<(446976 + 255) / 256, 256, 0, stream>>>(qkvw, projw, w1, w2, c1w,
                                                      wqkv, wprj, wfc1, wfc2, c1wb);

  // fused attention + LN1 + LCE conv1 (t1), writes x1 into d_out
  k_attn2<<<2048, 256, 0, stream>>>(x, n1g, n1b, wqkv, qkvb, rpb, wprj, projb,
                                    c1wb, c1b, t1, out);
  // FUSED: LCE conv3x3 (blocks 0..511) | MLP in-place on d_out (blocks 512..4607)
  k_mlp_lce2<<<4608, 256, 0, stream>>>(out, n2g, n2b, wfc1, b1, wfc2, b2,
                                       t1, c2w, c2b, t2);
  // FUSED: conv1x1 + LeakyReLU + pool partials
  k_lce3p<<<2048, 192, 0, stream>>>(t2, c3w, c3b, ybf, s0);
  // FUSED: SE gate + out += y*gate
  k_final2<<<2048, 256, 0, stream>>>(out, ybf, s0, sfc1, sfc2);
}

// Round 6
// 1006.741 us; speedup vs baseline: 1.4645x; 1.0961x over previous
//
#include <hip/hip_runtime.h>
#include <hip/hip_bf16.h>

using bf16 = __hip_bfloat16;
typedef __attribute__((ext_vector_type(8))) short short8;
typedef __attribute__((ext_vector_type(4))) float float4v;

constexpr int NTOK = 131072;  // 2*256*256

// ---------------- workspace layout (bytes) ----------------
constexpr size_t OFF_Y    = 0;           // (unused now)
constexpr size_t OFF_T1   = 50331648;    // f32  [131072][24]     12,582,912
constexpr size_t OFF_T2   = 62914560;    // f32  [131072][24]     12,582,912
constexpr size_t OFF_S0   = 75497472;    // f32  [2][192]
constexpr size_t OFF_SG   = 75499008;    // (unused)
constexpr size_t OFF_WQKV = 75500544;    // bf16 [576][192]       221,184
constexpr size_t OFF_WPRJ = 75721728;    // bf16 [192][192]        73,728
constexpr size_t OFF_WFC1 = 75795456;    // bf16 [768][192]       294,912
constexpr size_t OFF_WFC2 = 76090368;    // bf16 [192][768]       294,912
constexpr size_t OFF_C1WB = 76385280;    // bf16 [32][192]         12,288 (rows 24..31 zero)
constexpr size_t WS_NEEDED = 76397568;

__device__ __forceinline__ int region256(int t) { return t < 248 ? 0 : (t < 252 ? 1 : 2); }

__device__ __forceinline__ short8 lds8(const bf16* p) {
  return *reinterpret_cast<const short8*>(p);
}
__device__ __forceinline__ short8 glb8(const bf16* p) {
  return *reinterpret_cast<const short8*>(p);
}

// ---------------- fp32 -> bf16 weight convert + zero-init (one dispatch) ----------------
__global__ __launch_bounds__(256) void k_f2b_all(const float* __restrict__ qkvw, const float* __restrict__ projw,
                                                 const float* __restrict__ w1, const float* __restrict__ w2,
                                                 const float* __restrict__ c1w,
                                                 bf16* __restrict__ wqkv, bf16* __restrict__ wprj,
                                                 bf16* __restrict__ wfc1, bf16* __restrict__ wfc2,
                                                 bf16* __restrict__ c1wb, float* __restrict__ s0) {
  int i = blockIdx.x * 256 + threadIdx.x;
  if (i < 110592) { wqkv[i] = __float2bfloat16(qkvw[i]); return; }
  i -= 110592;
  if (i < 36864) { wprj[i] = __float2bfloat16(projw[i]); return; }
  i -= 36864;
  if (i < 147456) { wfc1[i] = __float2bfloat16(w1[i]); return; }
  i -= 147456;
  if (i < 147456) { wfc2[i] = __float2bfloat16(w2[i]); return; }
  i -= 147456;
  if (i < 4608) { c1wb[i] = __float2bfloat16(c1w[i]); return; }
  i -= 4608;
  if (i < 1536) { c1wb[4608 + i] = __float2bfloat16(0.f); return; }  // pad rows 24..31
  i -= 1536;
  if (i < 384) s0[i] = 0.f;
}

// ---------------- chunked fused attention (+ LCE conv1) ----------------
// R5: single-head chunks (6 x 1 head). LDS 40,960 B -> exactly 4 blocks/CU
// (4 x 40,960 = 163,840 = full 160 KiB pool). VGPR live-set shrinks vs R4
// (qreg 16->8), safely under the (256,4) cap of 128 -> no R3-style spill.
// Regions (same (r&7)<<4 XOR swizzle; verified 8 dword-accesses/bank on the
// 64-B-stride KL reads -> conflict-free):
//   STG @0      [64][192] bf16 stride 384 (LN rows, then O; wave-private rows)
//   KL1 @24576  [64 tok][32 ch] bf16 stride 64
//   VT1 @28672  [32 ch][64 tok] bf16 stride 128
//   PS3 @32768  [64][64]  bf16 stride 128 (per-wave Q/P scratch)
__device__ __forceinline__ int stg_b(int r, int c) { return (r * 384 + c * 2) ^ ((r & 7) << 4); }
__device__ __forceinline__ int kl1_b(int r, int c) { return 24576 + ((r * 64 + c * 2) ^ ((r & 7) << 4)); }
__device__ __forceinline__ int vt1_b(int r, int c) { return 28672 + ((r * 128 + c * 2) ^ ((r & 7) << 4)); }
__device__ __forceinline__ int ps3_b(int r, int c) { return 32768 + ((r * 128 + c * 2) ^ ((r & 7) << 4)); }

__device__ __forceinline__ short8 lds8o(const char* sm, int byteoff) {
  return *reinterpret_cast<const short8*>(sm + byteoff);
}
__device__ __forceinline__ void st16(char* sm, int byteoff, bf16 v) {
  *reinterpret_cast<bf16*>(sm + byteoff) = v;
}

__global__ __launch_bounds__(256, 4) void k_attn2(const float* __restrict__ x, const float* __restrict__ g,
                                                  const float* __restrict__ bb, const bf16* __restrict__ wq,
                                                  const float* __restrict__ qkvb, const float* __restrict__ rpb,
                                                  const bf16* __restrict__ wp, const float* __restrict__ projb,
                                                  const bf16* __restrict__ c1wb, const float* __restrict__ c1b,
                                                  float* __restrict__ t1, float* __restrict__ x1out) {
  __shared__ char sm[40960];

  int win = blockIdx.x;
  int b = win >> 10;
  int wrem = win & 1023;
  int wh = wrem >> 5, ww = wrem & 31;
  int tid = threadIdx.x;
  int wave = tid >> 6, lane = tid & 63;
  int colB = lane & 15, grp = lane >> 4;
  const float scale = 0.17677669529663687f;  // 1/sqrt(32)

  // ---- Phase 1: LN over this wave's 16 tokens (gather with roll -4) -> staging (wave-private rows)
  for (int t = 0; t < 16; ++t) {
    int tok = wave * 16 + t;
    int i = tok >> 3, j = tok & 7;
    int hp = (wh * 8 + i + 4) & 255;
    int wpp = (ww * 8 + j + 4) & 255;
    const float* xr = x + (((size_t)b << 16) + (hp << 8) + wpp) * 192;
    float v0 = xr[lane], v1 = xr[lane + 64], v2 = xr[lane + 128];
    float s = v0 + v1 + v2;
    for (int o = 32; o > 0; o >>= 1) s += __shfl_down(s, o);
    s = __shfl(s, 0);
    float m = s * (1.f / 192.f);
    float d0 = v0 - m, d1 = v1 - m, d2 = v2 - m;
    float q = d0 * d0 + d1 * d1 + d2 * d2;
    for (int o = 32; o > 0; o >>= 1) q += __shfl_down(q, o);
    q = __shfl(q, 0);
    float inv = rsqrtf(q * (1.f / 192.f) + 1e-5f);
    st16(sm, stg_b(tok, lane),       __float2bfloat16(d0 * inv * g[lane]       + bb[lane]));
    st16(sm, stg_b(tok, lane + 64),  __float2bfloat16(d1 * inv * g[lane + 64]  + bb[lane + 64]));
    st16(sm, stg_b(tok, lane + 128), __float2bfloat16(d2 * inv * g[lane + 128] + bb[lane + 128]));
  }

  // A-fragments of LN rows (same-wave LDS write->read, DS pipe in-order)
  short8 axw[6];
#pragma unroll
  for (int kk = 0; kk < 6; ++kk) axw[kk] = lds8o(sm, stg_b(wave * 16 + colB, kk * 32 + 8 * grp));

  int l1r[4], i1r[4], j1r[4];
#pragma unroll
  for (int r = 0; r < 4; ++r) {
    int n = wave * 16 + 4 * grp + r;
    i1r[r] = n >> 3; j1r[r] = n & 7;
    l1r[r] = region256(wh * 8 + i1r[r]) * 3 + region256(ww * 8 + j1r[r]);
  }

  for (int gch = 0; gch < 6; ++gch) {  // chunk = head gch = qkv cols 32g..32g+31
    float qreg[8];
    {  // Q (2 N-tiles)
      float4v qa[2] = {{0,0,0,0},{0,0,0,0}};
#pragma unroll
      for (int kk = 0; kk < 6; ++kk) {
#pragma unroll
        for (int jt = 0; jt < 2; ++jt) {
          int wrow = gch * 32 + jt * 16 + colB;
          qa[jt] = __builtin_amdgcn_mfma_f32_16x16x32_bf16(axw[kk], glb8(wq + (size_t)wrow * 192 + kk * 32 + 8 * grp), qa[jt], 0, 0, 0);
        }
      }
#pragma unroll
      for (int jt = 0; jt < 2; ++jt) {
        float bias = qkvb[gch * 32 + jt * 16 + colB];
#pragma unroll
        for (int r = 0; r < 4; ++r) qreg[jt * 4 + r] = (qa[jt][r] + bias) * scale;
      }
    }
    {  // K -> KL1 (rows = own tokens)
      float4v ka[2] = {{0,0,0,0},{0,0,0,0}};
#pragma unroll
      for (int kk = 0; kk < 6; ++kk) {
#pragma unroll
        for (int jt = 0; jt < 2; ++jt) {
          int wrow = 192 + gch * 32 + jt * 16 + colB;
          ka[jt] = __builtin_amdgcn_mfma_f32_16x16x32_bf16(axw[kk], glb8(wq + (size_t)wrow * 192 + kk * 32 + 8 * grp), ka[jt], 0, 0, 0);
        }
      }
#pragma unroll
      for (int jt = 0; jt < 2; ++jt) {
        float bias = qkvb[192 + gch * 32 + jt * 16 + colB];
#pragma unroll
        for (int r = 0; r < 4; ++r)
          st16(sm, kl1_b(wave * 16 + 4 * grp + r, jt * 16 + colB), __float2bfloat16(ka[jt][r] + bias));
      }
    }
    {  // V -> VT1 (transposed: rows = head-local channel, cols = own tokens)
      float4v va[2] = {{0,0,0,0},{0,0,0,0}};
#pragma unroll
      for (int kk = 0; kk < 6; ++kk) {
#pragma unroll
        for (int jt = 0; jt < 2; ++jt) {
          int wrow = 384 + gch * 32 + jt * 16 + colB;
          va[jt] = __builtin_amdgcn_mfma_f32_16x16x32_bf16(axw[kk], glb8(wq + (size_t)wrow * 192 + kk * 32 + 8 * grp), va[jt], 0, 0, 0);
        }
      }
#pragma unroll
      for (int jt = 0; jt < 2; ++jt) {
        float bias = qkvb[384 + gch * 32 + jt * 16 + colB];
#pragma unroll
        for (int r = 0; r < 4; ++r)
          st16(sm, vt1_b(jt * 16 + colB, wave * 16 + 4 * grp + r), __float2bfloat16(va[jt][r] + bias));
      }
    }
    if (gch == 0) {  // conv1 (LCE): 2 N-tiles, weights zero-padded to 32 rows
      float4v acc[2] = {{0,0,0,0},{0,0,0,0}};
#pragma unroll
      for (int kk = 0; kk < 6; ++kk) {
#pragma unroll
        for (int j = 0; j < 2; ++j) {
          int row = j * 16 + colB;
          acc[j] = __builtin_amdgcn_mfma_f32_16x16x32_bf16(axw[kk], glb8(c1wb + (size_t)row * 192 + kk * 32 + 8 * grp), acc[j], 0, 0, 0);
        }
      }
#pragma unroll
      for (int j = 0; j < 2; ++j) {
        int ch = j * 16 + colB;
        if (ch < 24) {
          float bias = c1b[ch];
#pragma unroll
          for (int r = 0; r < 4; ++r) {
            int tok = wave * 16 + 4 * grp + r;
            int i = tok >> 3, jj = tok & 7;
            int hp = (wh * 8 + i + 4) & 255;
            int wpp = (ww * 8 + jj + 4) & 255;
            size_t pix = ((size_t)b << 16) + (hp << 8) + wpp;
            t1[pix * 24 + ch] = acc[j][r] + bias;
          }
        }
      }
    }
    __syncthreads();  // K/V of this chunk visible to all waves

    {  // ---- attention for head h = gch (PS3/STG per-wave private)
      int h = gch;
#pragma unroll
      for (int t = 0; t < 2; ++t)
#pragma unroll
        for (int r = 0; r < 4; ++r)
          st16(sm, ps3_b(wave * 16 + 4 * grp + r, t * 16 + colB), __float2bfloat16(qreg[t * 4 + r]));
      short8 aq = lds8o(sm, ps3_b(wave * 16 + colB, 8 * grp));

      float4v s[4];
#pragma unroll
      for (int nt = 0; nt < 4; ++nt) {
        short8 bk = lds8o(sm, kl1_b(nt * 16 + colB, 8 * grp));
        float4v z = {0, 0, 0, 0};
        s[nt] = __builtin_amdgcn_mfma_f32_16x16x32_bf16(aq, bk, z, 0, 0, 0);
      }
#pragma unroll
      for (int nt = 0; nt < 4; ++nt) {
        int m = nt * 16 + colB;
        int i2 = m >> 3, j2 = m & 7;
        int l2 = region256(wh * 8 + i2) * 3 + region256(ww * 8 + j2);
#pragma unroll
        for (int r = 0; r < 4; ++r) {
          float bias = rpb[((i1r[r] - i2 + 7) * 15 + (j1r[r] - j2 + 7)) * 6 + h];
          s[nt][r] += bias + (l1r[r] != l2 ? -100.f : 0.f);
        }
      }
#pragma unroll
      for (int r = 0; r < 4; ++r) {
        float mx = fmaxf(fmaxf(s[0][r], s[1][r]), fmaxf(s[2][r], s[3][r]));
        mx = fmaxf(mx, __shfl_xor(mx, 1));
        mx = fmaxf(mx, __shfl_xor(mx, 2));
        mx = fmaxf(mx, __shfl_xor(mx, 4));
        mx = fmaxf(mx, __shfl_xor(mx, 8));
        float e0 = __expf(s[0][r] - mx), e1 = __expf(s[1][r] - mx);
        float e2 = __expf(s[2][r] - mx), e3 = __expf(s[3][r] - mx);
        float sum = e0 + e1 + e2 + e3;
        sum += __shfl_xor(sum, 1);
        sum += __shfl_xor(sum, 2);
        sum += __shfl_xor(sum, 4);
        sum += __shfl_xor(sum, 8);
        float inv = 1.f / sum;
        int row = wave * 16 + 4 * grp + r;
        st16(sm, ps3_b(row, 0 * 16 + colB), __float2bfloat16(e0 * inv));
        st16(sm, ps3_b(row, 1 * 16 + colB), __float2bfloat16(e1 * inv));
        st16(sm, ps3_b(row, 2 * 16 + colB), __float2bfloat16(e2 * inv));
        st16(sm, ps3_b(row, 3 * 16 + colB), __float2bfloat16(e3 * inv));
      }
      short8 ap0 = lds8o(sm, ps3_b(wave * 16 + colB, 8 * grp));
      short8 ap1 = lds8o(sm, ps3_b(wave * 16 + colB, 32 + 8 * grp));

      float4v o0 = {0, 0, 0, 0}, o1 = {0, 0, 0, 0};
      o0 = __builtin_amdgcn_mfma_f32_16x16x32_bf16(ap0, lds8o(sm, vt1_b(colB, 8 * grp)), o0, 0, 0, 0);
      o0 = __builtin_amdgcn_mfma_f32_16x16x32_bf16(ap1, lds8o(sm, vt1_b(colB, 32 + 8 * grp)), o0, 0, 0, 0);
      o1 = __builtin_amdgcn_mfma_f32_16x16x32_bf16(ap0, lds8o(sm, vt1_b(16 + colB, 8 * grp)), o1, 0, 0, 0);
      o1 = __builtin_amdgcn_mfma_f32_16x16x32_bf16(ap1, lds8o(sm, vt1_b(16 + colB, 32 + 8 * grp)), o1, 0, 0, 0);
      int ocol = gch * 32;
#pragma unroll
      for (int r = 0; r < 4; ++r) {
        int row = wave * 16 + 4 * grp + r;
        st16(sm, stg_b(row, ocol + colB),      __float2bfloat16(o0[r]));
        st16(sm, stg_b(row, ocol + 16 + colB), __float2bfloat16(o1[r]));
      }
    }
    if (gch != 5) __syncthreads();  // all waves done reading K/V before next chunk overwrites
  }

  // ---- Phase 4: proj + reverse-shift scatter + residual (O rows are wave-private)
  short8 ao[6];
#pragma unroll
  for (int kk = 0; kk < 6; ++kk) ao[kk] = lds8o(sm, stg_b(wave * 16 + colB, kk * 32 + 8 * grp));
  for (int gp = 0; gp < 4; ++gp) {
    float4v acc[3] = {{0,0,0,0},{0,0,0,0},{0,0,0,0}};
#pragma unroll
    for (int kk = 0; kk < 6; ++kk) {
#pragma unroll
      for (int j = 0; j < 3; ++j) {
        int col = (gp * 3 + j) * 16 + colB;
        acc[j] = __builtin_amdgcn_mfma_f32_16x16x32_bf16(ao[kk], glb8(wp + (size_t)col * 192 + kk * 32 + 8 * grp), acc[j], 0, 0, 0);
      }
    }
#pragma unroll
    for (int j = 0; j < 3; ++j) {
      int col = (gp * 3 + j) * 16 + colB;
      float bias = projb[col];
#pragma unroll
      for (int r = 0; r < 4; ++r) {
        int n = wave * 16 + 4 * grp + r;
        int i = n >> 3, jj = n & 7;
        int hd2 = (wh * 8 + i + 4) & 255;
        int wd2 = (ww * 8 + jj + 4) & 255;
        size_t p = (((size_t)b << 16) + (hd2 << 8) + wd2) * 192 + col;
        x1out[p] = x[p] + acc[j][r] + bias;
      }
    }
  }
}

// ---------------- FUSED: [LCE conv3x3 + conv1x1-pool (512 blocks)] | [MFMA MLP (4096 blocks)] ----------------
// conv blocks now ALSO compute the conv1x1+LeakyReLU pool partials (s0) from
// their in-register t2 tile -> y buffer and the k_lce3p dispatch are gone.
__global__ __launch_bounds__(256, 2) void k_mlp_lce2(float* __restrict__ x1, const float* __restrict__ g,
                                                     const float* __restrict__ bb, const bf16* __restrict__ w1,
                                                     const float* __restrict__ b1, const bf16* __restrict__ w2,
                                                     const float* __restrict__ b2,
                                                     const float* __restrict__ t1, const float* __restrict__ cw,
                                                     const float* __restrict__ cbia, float* __restrict__ t2,
                                                     const float* __restrict__ c3w, const float* __restrict__ c3b,
                                                     float* __restrict__ s0) {
  __shared__ __align__(16) char smu[62464];
  int tid = threadIdx.x;

  if (blockIdx.x < 512) {
    // ---------- LCE conv3x3 24->24 ----------
    float* halo = (float*)smu;            // 18*18*25 floats = 32,400 B
    float* wlds = (float*)(smu + 32400);  // 5184 floats = 20,736 B
    int bid = blockIdx.x;
    int b = bid >> 8;
    int rem = bid & 255;
    int ty0 = ((rem >> 4) & 15) * 16, tx0 = (rem & 15) * 16;
    for (int idx = tid; idx < 5184; idx += 256) wlds[idx] = cw[idx];
    for (int idx = tid; idx < 18 * 18 * 24; idx += 256) {
      int ch = idx % 24;
      int pp = idx / 24;
      int hy = pp / 18, hx = pp - hy * 18;
      int gy = ty0 + hy - 1, gx = tx0 + hx - 1;
      float v = 0.f;
      if (gy >= 0 && gy < 256 && gx >= 0 && gx < 256)
        v = t1[((size_t)(b << 16) + (gy << 8) + gx) * 24 + ch];
      halo[pp * 25 + ch] = v;
    }
    __syncthreads();
    int py = tid >> 4, px = tid & 15;
    float acc[24];
#pragma unroll
    for (int ro = 0; ro < 24; ++ro) acc[ro] = cbia[ro];
    for (int ky = 0; ky < 3; ++ky) {
      for (int kx = 0; kx < 3; ++kx) {
        int base = ((py + ky) * 18 + px + kx) * 25;
        float inb[24];
#pragma unroll
        for (int ri = 0; ri < 24; ++ri) inb[ri] = halo[base + ri];
        int wo = ky * 3 + kx;
#pragma unroll
        for (int ro = 0; ro < 24; ++ro) {
          float a = acc[ro];
#pragma unroll
          for (int ri = 0; ri < 24; ++ri) a += inb[ri] * wlds[ro * 216 + ri * 9 + wo];
          acc[ro] = a;
        }
      }
    }
    size_t pix = (size_t)(b << 16) + ((ty0 + py) << 8) + tx0 + px;
#pragma unroll
    for (int ro = 0; ro < 24; ++ro) t2[pix * 24 + ro] = acc[ro];

    // ---------- conv1x1 24->192 + LeakyReLU pool partials (y never materialized) ----------
    __syncthreads();                     // all halo reads complete
    float* t2l = (float*)smu;            // [256][28] floats = 28,672 B (16B-aligned rows)
#pragma unroll
    for (int ro = 0; ro < 24; ++ro) t2l[tid * 28 + ro] = acc[ro];
    __syncthreads();
    if (tid < 192) {
      float wr3[24];
#pragma unroll
      for (int i2 = 0; i2 < 24; ++i2) wr3[i2] = c3w[tid * 24 + i2];
      float b3 = c3b[tid];
      float ps = 0.f;
      for (int p = 0; p < 256; ++p) {
        const float4v* rp = reinterpret_cast<const float4v*>(&t2l[p * 28]);
        float a = b3;
#pragma unroll
        for (int v = 0; v < 6; ++v) {
          float4v q = rp[v];
          a += q[0] * wr3[v * 4] + q[1] * wr3[v * 4 + 1] + q[2] * wr3[v * 4 + 2] + q[3] * wr3[v * 4 + 3];
        }
        ps += (a < 0.f) ? 0.2f * a : a;
      }
      atomicAdd(&s0[b * 192 + tid], ps);
    }
    return;
  }

  // ---------- MFMA MLP: LN2 + fc1 + GELU + fc2 + residual (in-place) ----------
  bf16 (*xl)[200] = reinterpret_cast<bf16(*)[200]>(smu);            // 12,800 B
  bf16 (*hh)[776] = reinterpret_cast<bf16(*)[776]>(smu + 12800);    // 49,664 B
  int wave = tid >> 6, lane = tid & 63;
  int colB = lane & 15, grp = lane >> 4;
  size_t tokbase = (size_t)(blockIdx.x - 512) * 32;

  for (int t = wave; t < 32; t += 4) {
    const float* xr = x1 + (tokbase + t) * 192;
    float v0 = xr[lane], v1 = xr[lane + 64], v2 = xr[lane + 128];
    float s = v0 + v1 + v2;
    for (int o = 32; o > 0; o >>= 1) s += __shfl_down(s, o);
    s = __shfl(s, 0);
    float m = s * (1.f / 192.f);
    float d0 = v0 - m, d1 = v1 - m, d2 = v2 - m;
    float qq = d0 * d0 + d1 * d1 + d2 * d2;
    for (int o = 32; o > 0; o >>= 1) qq += __shfl_down(qq, o);
    qq = __shfl(qq, 0);
    float inv = rsqrtf(qq * (1.f / 192.f) + 1e-5f);
    xl[t][lane]       = __float2bfloat16(d0 * inv * g[lane]       + bb[lane]);
    xl[t][lane + 64]  = __float2bfloat16(d1 * inv * g[lane + 64]  + bb[lane + 64]);
    xl[t][lane + 128] = __float2bfloat16(d2 * inv * g[lane + 128] + bb[lane + 128]);
  }
  __syncthreads();

  short8 a1f[6][2];
#pragma unroll
  for (int kk = 0; kk < 6; ++kk) {
    a1f[kk][0] = lds8(&xl[colB][kk * 32 + 8 * grp]);
    a1f[kk][1] = lds8(&xl[16 + colB][kk * 32 + 8 * grp]);
  }
  for (int nn = 0; nn < 12; ++nn) {
    int nt = wave * 12 + nn;
    float4v c0 = {0, 0, 0, 0}, c1 = {0, 0, 0, 0};
#pragma unroll
    for (int kk = 0; kk < 6; ++kk) {
      short8 bw = glb8(w1 + (size_t)(nt * 16 + colB) * 192 + kk * 32 + 8 * grp);
      c0 = __builtin_amdgcn_mfma_f32_16x16x32_bf16(a1f[kk][0], bw, c0, 0, 0, 0);
      c1 = __builtin_amdgcn_mfma_f32_16x16x32_bf16(a1f[kk][1], bw, c1, 0, 0, 0);
    }
    int col = nt * 16 + colB;
    float bias = b1[col];
#pragma unroll
    for (int r = 0; r < 4; ++r) {
      float v0 = c0[r] + bias;
      float v1 = c1[r] + bias;
      v0 = v0 * 0.5f * (1.f + erff(v0 * 0.70710678118654752f));
      v1 = v1 * 0.5f * (1.f + erff(v1 * 0.70710678118654752f));
      hh[4 * grp + r][col] = __float2bfloat16(v0);
      hh[16 + 4 * grp + r][col] = __float2bfloat16(v1);
    }
  }
  __syncthreads();

  float4v d0[3] = {{0,0,0,0},{0,0,0,0},{0,0,0,0}};
  float4v d1[3] = {{0,0,0,0},{0,0,0,0},{0,0,0,0}};
  int ntb = wave * 3;
  for (int kk = 0; kk < 24; ++kk) {
    int ko = kk * 32 + 8 * grp;
    short8 h0 = lds8(&hh[colB][ko]);
    short8 h1 = lds8(&hh[16 + colB][ko]);
#pragma unroll
    for (int j = 0; j < 3; ++j) {
      short8 bw = glb8(w2 + (size_t)((ntb + j) * 16 + colB) * 768 + ko);
      d0[j] = __builtin_amdgcn_mfma_f32_16x16x32_bf16(h0, bw, d0[j], 0, 0, 0);
      d1[j] = __builtin_amdgcn_mfma_f32_16x16x32_bf16(h1, bw, d1[j], 0, 0, 0);
    }
  }
#pragma unroll
  for (int j = 0; j < 3; ++j) {
    int col = (ntb + j) * 16 + colB;
    float bias = b2[col];
#pragma unroll
    for (int r = 0; r < 4; ++r) {
      size_t p0 = (tokbase + 4 * grp + r) * 192 + col;
      size_t p1 = (tokbase + 16 + 4 * grp + r) * 192 + col;
      x1[p0] += d0[j][r] + bias;
      x1[p1] += d1[j][r] + bias;
    }
  }
}

// ---------------- FUSED: SE gate + conv1x1 recompute + out += y*gate ----------------
// 2048 blocks x 192 threads; thread c recomputes y from t2 (staged in LDS) for
// its channel over 64 pixels. Replaces lce3p+final2; saves the 100 MB y round-trip.
__global__ __launch_bounds__(192) void k_final3(float* __restrict__ out, const float* __restrict__ t2,
                                                const float* __restrict__ c3w, const float* __restrict__ c3b,
                                                const float* __restrict__ s0, const float* __restrict__ w1se,
                                                const float* __restrict__ w2se) {
  __shared__ float mean[192];
  __shared__ float tt[24];
  __shared__ __align__(16) float t2l[64 * 24];
  int b = blockIdx.x >> 10;
  int chunk = blockIdx.x & 1023;
  int tid = threadIdx.x;  // 0..191
  mean[tid] = s0[b * 192 + tid] * (1.f / 65536.f);
  size_t pix0 = (size_t)b * 65536 + chunk * 64;
  for (int idx = tid; idx < 1536; idx += 192) t2l[idx] = t2[pix0 * 24 + idx];
  __syncthreads();
  if (tid < 24) {
    float a = 0.f;
    for (int c = 0; c < 192; ++c) a += mean[c] * w1se[tid * 192 + c];
    tt[tid] = fmaxf(a, 0.f);
  }
  __syncthreads();
  float a = 0.f;
#pragma unroll
  for (int r = 0; r < 24; ++r) a += tt[r] * w2se[tid * 24 + r];
  float gate = 1.f / (1.f + expf(-a));

  float wr3[24];
#pragma unroll
  for (int i = 0; i < 24; ++i) wr3[i] = c3w[tid * 24 + i];
  float b3 = c3b[tid];
  for (int p = 0; p < 64; ++p) {
    const float4v* rp = reinterpret_cast<const float4v*>(&t2l[p * 24]);
    float acc = b3;
#pragma unroll
    for (int v = 0; v < 6; ++v) {
      float4v q = rp[v];
      acc += q[0] * wr3[v * 4] + q[1] * wr3[v * 4 + 1] + q[2] * wr3[v * 4 + 2] + q[3] * wr3[v * 4 + 3];
    }
    if (acc < 0.f) acc *= 0.2f;
    out[(pix0 + p) * 192 + tid] += acc * gate;
  }
}

extern "C" void kernel_launch(void* const* d_in, const int* in_sizes, int n_in,
                              void* d_out, int out_size, void* d_ws, size_t ws_size,
                              hipStream_t stream) {
  const float* x     = (const float*)d_in[0];
  const float* n1g   = (const float*)d_in[1];
  const float* n1b   = (const float*)d_in[2];
  const float* qkvw  = (const float*)d_in[3];
  const float* qkvb  = (const float*)d_in[4];
  const float* rpb   = (const float*)d_in[5];
  const float* projw = (const float*)d_in[6];
  const float* projb = (const float*)d_in[7];
  const float* n2g   = (const float*)d_in[8];
  const float* n2b   = (const float*)d_in[9];
  const float* w1    = (const float*)d_in[10];
  const float* b1    = (const float*)d_in[11];
  const float* w2    = (const float*)d_in[12];
  const float* b2    = (const float*)d_in[13];
  const float* c1w   = (const float*)d_in[14];
  const float* c1b   = (const float*)d_in[15];
  const float* c2w   = (const float*)d_in[16];
  const float* c2b   = (const float*)d_in[17];
  const float* c3w   = (const float*)d_in[18];
  const float* c3b   = (const float*)d_in[19];
  const float* sfc1  = (const float*)d_in[20];
  const float* sfc2  = (const float*)d_in[21];
  float* out = (float*)d_out;

  if (ws_size < WS_NEEDED) return;

  char* ws = (char*)d_ws;
  float* t1   = (float*)(ws + OFF_T1);
  float* t2   = (float*)(ws + OFF_T2);
  float* s0   = (float*)(ws + OFF_S0);
  bf16*  wqkv = (bf16*)(ws + OFF_WQKV);
  bf16*  wprj = (bf16*)(ws + OFF_WPRJ);
  bf16*  wfc1 = (bf16*)(ws + OFF_WFC1);
  bf16*  wfc2 = (bf16*)(ws + OFF_WFC2);
  bf16*  c1wb = (bf16*)(ws + OFF_C1WB);

  // weight converts + c1wb zero-pad + s0 zero, one dispatch (448,896 elements)
  k_f2b_all<<<1754, 256, 0, stream>>>(qkvw, projw, w1, w2, c1w,
                                      wqkv, wprj, wfc1, wfc2, c1wb, s0);

  // fused attention + LN1 + LCE conv1 (t1), writes x1 into d_out
  k_attn2<<<2048, 256, 0, stream>>>(x, n1g, n1b, wqkv, qkvb, rpb, wprj, projb,
                                    c1wb, c1b, t1, out);
  // FUSED: LCE conv3x3 + pool (blocks 0..511) | MLP in-place on d_out (blocks 512..4607)
  k_mlp_lce2<<<4608, 256, 0, stream>>>(out, n2g, n2b, wfc1, b1, wfc2, b2,
                                       t1, c2w, c2b, t2, c3w, c3b, s0);
  // FUSED: SE gate + conv1x1 recompute + out += y*gate
  k_final3<<<2048, 192, 0, stream>>>(out, t2, c3w, c3b, s0, sfc1, sfc2);
}

// Round 7
// 904.901 us; speedup vs baseline: 1.6294x; 1.1125x over previous
//
#include <hip/hip_runtime.h>
#include <hip/hip_bf16.h>

using bf16 = __hip_bfloat16;
typedef __attribute__((ext_vector_type(8))) short short8;
typedef __attribute__((ext_vector_type(4))) float float4v;

constexpr int NTOK = 131072;  // 2*256*256

// ---------------- workspace layout (bytes) ----------------
constexpr size_t OFF_T1   = 50331648;    // f32  [131072][24]     12,582,912
constexpr size_t OFF_T2   = 62914560;    // f32  [131072][24]     12,582,912
constexpr size_t OFF_S0   = 75497472;    // f32  [2][192]
constexpr size_t OFF_WQKV = 75500544;    // bf16 [576][192]       221,184
constexpr size_t OFF_WPRJ = 75721728;    // bf16 [192][192]        73,728
constexpr size_t OFF_WFC1 = 75795456;    // bf16 [768][192]       294,912
constexpr size_t OFF_WFC2 = 76090368;    // bf16 [192][768]       294,912
constexpr size_t OFF_C1WB = 76385280;    // bf16 [32][192]         12,288 (rows 24..31 zero)
constexpr size_t WS_NEEDED = 76397568;

__device__ __forceinline__ int region256(int t) { return t < 248 ? 0 : (t < 252 ? 1 : 2); }

__device__ __forceinline__ short8 lds8(const bf16* p) {
  return *reinterpret_cast<const short8*>(p);
}
__device__ __forceinline__ short8 glb8(const bf16* p) {
  return *reinterpret_cast<const short8*>(p);
}

// ---------------- fp32 -> bf16 weight convert + zero-init (one dispatch) ----------------
__global__ __launch_bounds__(256) void k_f2b_all(const float* __restrict__ qkvw, const float* __restrict__ projw,
                                                 const float* __restrict__ w1, const float* __restrict__ w2,
                                                 const float* __restrict__ c1w,
                                                 bf16* __restrict__ wqkv, bf16* __restrict__ wprj,
                                                 bf16* __restrict__ wfc1, bf16* __restrict__ wfc2,
                                                 bf16* __restrict__ c1wb, float* __restrict__ s0) {
  int i = blockIdx.x * 256 + threadIdx.x;
  if (i < 110592) { wqkv[i] = __float2bfloat16(qkvw[i]); return; }
  i -= 110592;
  if (i < 36864) { wprj[i] = __float2bfloat16(projw[i]); return; }
  i -= 36864;
  if (i < 147456) { wfc1[i] = __float2bfloat16(w1[i]); return; }
  i -= 147456;
  if (i < 147456) { wfc2[i] = __float2bfloat16(w2[i]); return; }
  i -= 147456;
  if (i < 4608) { c1wb[i] = __float2bfloat16(c1w[i]); return; }
  i -= 4608;
  if (i < 1536) { c1wb[4608 + i] = __float2bfloat16(0.f); return; }  // pad rows 24..31
  i -= 1536;
  if (i < 384) s0[i] = 0.f;
}

// ---------------- chunked fused attention (+ LCE conv1) — unchanged from R5 ----------------
__device__ __forceinline__ int stg_b(int r, int c) { return (r * 384 + c * 2) ^ ((r & 7) << 4); }
__device__ __forceinline__ int kl1_b(int r, int c) { return 24576 + ((r * 64 + c * 2) ^ ((r & 7) << 4)); }
__device__ __forceinline__ int vt1_b(int r, int c) { return 28672 + ((r * 128 + c * 2) ^ ((r & 7) << 4)); }
__device__ __forceinline__ int ps3_b(int r, int c) { return 32768 + ((r * 128 + c * 2) ^ ((r & 7) << 4)); }

__device__ __forceinline__ short8 lds8o(const char* sm, int byteoff) {
  return *reinterpret_cast<const short8*>(sm + byteoff);
}
__device__ __forceinline__ void st16(char* sm, int byteoff, bf16 v) {
  *reinterpret_cast<bf16*>(sm + byteoff) = v;
}

__global__ __launch_bounds__(256, 4) void k_attn2(const float* __restrict__ x, const float* __restrict__ g,
                                                  const float* __restrict__ bb, const bf16* __restrict__ wq,
                                                  const float* __restrict__ qkvb, const float* __restrict__ rpb,
                                                  const bf16* __restrict__ wp, const float* __restrict__ projb,
                                                  const bf16* __restrict__ c1wb, const float* __restrict__ c1b,
                                                  float* __restrict__ t1, float* __restrict__ x1out) {
  __shared__ char sm[40960];

  int win = blockIdx.x;
  int b = win >> 10;
  int wrem = win & 1023;
  int wh = wrem >> 5, ww = wrem & 31;
  int tid = threadIdx.x;
  int wave = tid >> 6, lane = tid & 63;
  int colB = lane & 15, grp = lane >> 4;
  const float scale = 0.17677669529663687f;  // 1/sqrt(32)

  for (int t = 0; t < 16; ++t) {
    int tok = wave * 16 + t;
    int i = tok >> 3, j = tok & 7;
    int hp = (wh * 8 + i + 4) & 255;
    int wpp = (ww * 8 + j + 4) & 255;
    const float* xr = x + (((size_t)b << 16) + (hp << 8) + wpp) * 192;
    float v0 = xr[lane], v1 = xr[lane + 64], v2 = xr[lane + 128];
    float s = v0 + v1 + v2;
    for (int o = 32; o > 0; o >>= 1) s += __shfl_down(s, o);
    s = __shfl(s, 0);
    float m = s * (1.f / 192.f);
    float d0 = v0 - m, d1 = v1 - m, d2 = v2 - m;
    float q = d0 * d0 + d1 * d1 + d2 * d2;
    for (int o = 32; o > 0; o >>= 1) q += __shfl_down(q, o);
    q = __shfl(q, 0);
    float inv = rsqrtf(q * (1.f / 192.f) + 1e-5f);
    st16(sm, stg_b(tok, lane),       __float2bfloat16(d0 * inv * g[lane]       + bb[lane]));
    st16(sm, stg_b(tok, lane + 64),  __float2bfloat16(d1 * inv * g[lane + 64]  + bb[lane + 64]));
    st16(sm, stg_b(tok, lane + 128), __float2bfloat16(d2 * inv * g[lane + 128] + bb[lane + 128]));
  }

  short8 axw[6];
#pragma unroll
  for (int kk = 0; kk < 6; ++kk) axw[kk] = lds8o(sm, stg_b(wave * 16 + colB, kk * 32 + 8 * grp));

  int l1r[4], i1r[4], j1r[4];
#pragma unroll
  for (int r = 0; r < 4; ++r) {
    int n = wave * 16 + 4 * grp + r;
    i1r[r] = n >> 3; j1r[r] = n & 7;
    l1r[r] = region256(wh * 8 + i1r[r]) * 3 + region256(ww * 8 + j1r[r]);
  }

  for (int gch = 0; gch < 6; ++gch) {  // chunk = head gch = qkv cols 32g..32g+31
    float qreg[8];
    {  // Q (2 N-tiles)
      float4v qa[2] = {{0,0,0,0},{0,0,0,0}};
#pragma unroll
      for (int kk = 0; kk < 6; ++kk) {
#pragma unroll
        for (int jt = 0; jt < 2; ++jt) {
          int wrow = gch * 32 + jt * 16 + colB;
          qa[jt] = __builtin_amdgcn_mfma_f32_16x16x32_bf16(axw[kk], glb8(wq + (size_t)wrow * 192 + kk * 32 + 8 * grp), qa[jt], 0, 0, 0);
        }
      }
#pragma unroll
      for (int jt = 0; jt < 2; ++jt) {
        float bias = qkvb[gch * 32 + jt * 16 + colB];
#pragma unroll
        for (int r = 0; r < 4; ++r) qreg[jt * 4 + r] = (qa[jt][r] + bias) * scale;
      }
    }
    {  // K -> KL1
      float4v ka[2] = {{0,0,0,0},{0,0,0,0}};
#pragma unroll
      for (int kk = 0; kk < 6; ++kk) {
#pragma unroll
        for (int jt = 0; jt < 2; ++jt) {
          int wrow = 192 + gch * 32 + jt * 16 + colB;
          ka[jt] = __builtin_amdgcn_mfma_f32_16x16x32_bf16(axw[kk], glb8(wq + (size_t)wrow * 192 + kk * 32 + 8 * grp), ka[jt], 0, 0, 0);
        }
      }
#pragma unroll
      for (int jt = 0; jt < 2; ++jt) {
        float bias = qkvb[192 + gch * 32 + jt * 16 + colB];
#pragma unroll
        for (int r = 0; r < 4; ++r)
          st16(sm, kl1_b(wave * 16 + 4 * grp + r, jt * 16 + colB), __float2bfloat16(ka[jt][r] + bias));
      }
    }
    {  // V -> VT1 (transposed)
      float4v va[2] = {{0,0,0,0},{0,0,0,0}};
#pragma unroll
      for (int kk = 0; kk < 6; ++kk) {
#pragma unroll
        for (int jt = 0; jt < 2; ++jt) {
          int wrow = 384 + gch * 32 + jt * 16 + colB;
          va[jt] = __builtin_amdgcn_mfma_f32_16x16x32_bf16(axw[kk], glb8(wq + (size_t)wrow * 192 + kk * 32 + 8 * grp), va[jt], 0, 0, 0);
        }
      }
#pragma unroll
      for (int jt = 0; jt < 2; ++jt) {
        float bias = qkvb[384 + gch * 32 + jt * 16 + colB];
#pragma unroll
        for (int r = 0; r < 4; ++r)
          st16(sm, vt1_b(jt * 16 + colB, wave * 16 + 4 * grp + r), __float2bfloat16(va[jt][r] + bias));
      }
    }
    if (gch == 0) {  // conv1 (LCE)
      float4v acc[2] = {{0,0,0,0},{0,0,0,0}};
#pragma unroll
      for (int kk = 0; kk < 6; ++kk) {
#pragma unroll
        for (int j = 0; j < 2; ++j) {
          int row = j * 16 + colB;
          acc[j] = __builtin_amdgcn_mfma_f32_16x16x32_bf16(axw[kk], glb8(c1wb + (size_t)row * 192 + kk * 32 + 8 * grp), acc[j], 0, 0, 0);
        }
      }
#pragma unroll
      for (int j = 0; j < 2; ++j) {
        int ch = j * 16 + colB;
        if (ch < 24) {
          float bias = c1b[ch];
#pragma unroll
          for (int r = 0; r < 4; ++r) {
            int tok = wave * 16 + 4 * grp + r;
            int i = tok >> 3, jj = tok & 7;
            int hp = (wh * 8 + i + 4) & 255;
            int wpp = (ww * 8 + jj + 4) & 255;
            size_t pix = ((size_t)b << 16) + (hp << 8) + wpp;
            t1[pix * 24 + ch] = acc[j][r] + bias;
          }
        }
      }
    }
    __syncthreads();

    {  // attention for head h = gch
      int h = gch;
#pragma unroll
      for (int t = 0; t < 2; ++t)
#pragma unroll
        for (int r = 0; r < 4; ++r)
          st16(sm, ps3_b(wave * 16 + 4 * grp + r, t * 16 + colB), __float2bfloat16(qreg[t * 4 + r]));
      short8 aq = lds8o(sm, ps3_b(wave * 16 + colB, 8 * grp));

      float4v s[4];
#pragma unroll
      for (int nt = 0; nt < 4; ++nt) {
        short8 bk = lds8o(sm, kl1_b(nt * 16 + colB, 8 * grp));
        float4v z = {0, 0, 0, 0};
        s[nt] = __builtin_amdgcn_mfma_f32_16x16x32_bf16(aq, bk, z, 0, 0, 0);
      }
#pragma unroll
      for (int nt = 0; nt < 4; ++nt) {
        int m = nt * 16 + colB;
        int i2 = m >> 3, j2 = m & 7;
        int l2 = region256(wh * 8 + i2) * 3 + region256(ww * 8 + j2);
#pragma unroll
        for (int r = 0; r < 4; ++r) {
          float bias = rpb[((i1r[r] - i2 + 7) * 15 + (j1r[r] - j2 + 7)) * 6 + h];
          s[nt][r] += bias + (l1r[r] != l2 ? -100.f : 0.f);
        }
      }
#pragma unroll
      for (int r = 0; r < 4; ++r) {
        float mx = fmaxf(fmaxf(s[0][r], s[1][r]), fmaxf(s[2][r], s[3][r]));
        mx = fmaxf(mx, __shfl_xor(mx, 1));
        mx = fmaxf(mx, __shfl_xor(mx, 2));
        mx = fmaxf(mx, __shfl_xor(mx, 4));
        mx = fmaxf(mx, __shfl_xor(mx, 8));
        float e0 = __expf(s[0][r] - mx), e1 = __expf(s[1][r] - mx);
        float e2 = __expf(s[2][r] - mx), e3 = __expf(s[3][r] - mx);
        float sum = e0 + e1 + e2 + e3;
        sum += __shfl_xor(sum, 1);
        sum += __shfl_xor(sum, 2);
        sum += __shfl_xor(sum, 4);
        sum += __shfl_xor(sum, 8);
        float inv = 1.f / sum;
        int row = wave * 16 + 4 * grp + r;
        st16(sm, ps3_b(row, 0 * 16 + colB), __float2bfloat16(e0 * inv));
        st16(sm, ps3_b(row, 1 * 16 + colB), __float2bfloat16(e1 * inv));
        st16(sm, ps3_b(row, 2 * 16 + colB), __float2bfloat16(e2 * inv));
        st16(sm, ps3_b(row, 3 * 16 + colB), __float2bfloat16(e3 * inv));
      }
      short8 ap0 = lds8o(sm, ps3_b(wave * 16 + colB, 8 * grp));
      short8 ap1 = lds8o(sm, ps3_b(wave * 16 + colB, 32 + 8 * grp));

      float4v o0 = {0, 0, 0, 0}, o1 = {0, 0, 0, 0};
      o0 = __builtin_amdgcn_mfma_f32_16x16x32_bf16(ap0, lds8o(sm, vt1_b(colB, 8 * grp)), o0, 0, 0, 0);
      o0 = __builtin_amdgcn_mfma_f32_16x16x32_bf16(ap1, lds8o(sm, vt1_b(colB, 32 + 8 * grp)), o0, 0, 0, 0);
      o1 = __builtin_amdgcn_mfma_f32_16x16x32_bf16(ap0, lds8o(sm, vt1_b(16 + colB, 8 * grp)), o1, 0, 0, 0);
      o1 = __builtin_amdgcn_mfma_f32_16x16x32_bf16(ap1, lds8o(sm, vt1_b(16 + colB, 32 + 8 * grp)), o1, 0, 0, 0);
      int ocol = gch * 32;
#pragma unroll
      for (int r = 0; r < 4; ++r) {
        int row = wave * 16 + 4 * grp + r;
        st16(sm, stg_b(row, ocol + colB),      __float2bfloat16(o0[r]));
        st16(sm, stg_b(row, ocol + 16 + colB), __float2bfloat16(o1[r]));
      }
    }
    if (gch != 5) __syncthreads();
  }

  // ---- proj + reverse-shift scatter + residual
  short8 ao[6];
#pragma unroll
  for (int kk = 0; kk < 6; ++kk) ao[kk] = lds8o(sm, stg_b(wave * 16 + colB, kk * 32 + 8 * grp));
  for (int gp = 0; gp < 4; ++gp) {
    float4v acc[3] = {{0,0,0,0},{0,0,0,0},{0,0,0,0}};
#pragma unroll
    for (int kk = 0; kk < 6; ++kk) {
#pragma unroll
      for (int j = 0; j < 3; ++j) {
        int col = (gp * 3 + j) * 16 + colB;
        acc[j] = __builtin_amdgcn_mfma_f32_16x16x32_bf16(ao[kk], glb8(wp + (size_t)col * 192 + kk * 32 + 8 * grp), acc[j], 0, 0, 0);
      }
    }
#pragma unroll
    for (int j = 0; j < 3; ++j) {
      int col = (gp * 3 + j) * 16 + colB;
      float bias = projb[col];
#pragma unroll
      for (int r = 0; r < 4; ++r) {
        int n = wave * 16 + 4 * grp + r;
        int i = n >> 3, jj = n & 7;
        int hd2 = (wh * 8 + i + 4) & 255;
        int wd2 = (ww * 8 + jj + 4) & 255;
        size_t p = (((size_t)b << 16) + (hd2 << 8) + wd2) * 192 + col;
        x1out[p] = x[p] + acc[j][r] + bias;
      }
    }
  }
}

// ---------------- FUSED: [LCE conv3x3 + conv1x1-pool (512 blocks)] | [MFMA MLP 64-tok (2048 blocks)] ----------------
// R6: MLP blocks now process 64 tokens (4 token-tiles) so every global weight
// fragment feeds 4 MFMAs (was 2) — halves per-token L2-latency exposure, the
// measured bottleneck (MfmaUtil 6.9%, all pipes idle). hh split into two
// 384-col halves w/ fc2 partials in regs (d[3][4], 48 VGPR, no spill at cap
// 256). LDS = xl[64][200] + hh[64][392] = 75,776 B dynamic -> 2 blocks/CU.
__global__ __launch_bounds__(256, 2) void k_mlp_lce2(float* __restrict__ x1, const float* __restrict__ g,
                                                     const float* __restrict__ bb, const bf16* __restrict__ w1,
                                                     const float* __restrict__ b1, const bf16* __restrict__ w2,
                                                     const float* __restrict__ b2,
                                                     const float* __restrict__ t1, const float* __restrict__ cw,
                                                     const float* __restrict__ cbia, float* __restrict__ t2,
                                                     const float* __restrict__ c3w, const float* __restrict__ c3b,
                                                     float* __restrict__ s0) {
  extern __shared__ __align__(16) char smu[];
  int tid = threadIdx.x;

  if (blockIdx.x < 512) {
    // ---------- LCE conv3x3 24->24 ----------
    float* halo = (float*)smu;            // 18*18*25 floats = 32,400 B
    float* wlds = (float*)(smu + 32400);  // 5184 floats = 20,736 B
    int bid = blockIdx.x;
    int b = bid >> 8;
    int rem = bid & 255;
    int ty0 = ((rem >> 4) & 15) * 16, tx0 = (rem & 15) * 16;
    for (int idx = tid; idx < 5184; idx += 256) wlds[idx] = cw[idx];
    for (int idx = tid; idx < 18 * 18 * 24; idx += 256) {
      int ch = idx % 24;
      int pp = idx / 24;
      int hy = pp / 18, hx = pp - hy * 18;
      int gy = ty0 + hy - 1, gx = tx0 + hx - 1;
      float v = 0.f;
      if (gy >= 0 && gy < 256 && gx >= 0 && gx < 256)
        v = t1[((size_t)(b << 16) + (gy << 8) + gx) * 24 + ch];
      halo[pp * 25 + ch] = v;
    }
    __syncthreads();
    int py = tid >> 4, px = tid & 15;
    float acc[24];
#pragma unroll
    for (int ro = 0; ro < 24; ++ro) acc[ro] = cbia[ro];
    for (int ky = 0; ky < 3; ++ky) {
      for (int kx = 0; kx < 3; ++kx) {
        int base = ((py + ky) * 18 + px + kx) * 25;
        float inb[24];
#pragma unroll
        for (int ri = 0; ri < 24; ++ri) inb[ri] = halo[base + ri];
        int wo = ky * 3 + kx;
#pragma unroll
        for (int ro = 0; ro < 24; ++ro) {
          float a = acc[ro];
#pragma unroll
          for (int ri = 0; ri < 24; ++ri) a += inb[ri] * wlds[ro * 216 + ri * 9 + wo];
          acc[ro] = a;
        }
      }
    }
    size_t pix = (size_t)(b << 16) + ((ty0 + py) << 8) + tx0 + px;
#pragma unroll
    for (int ro = 0; ro < 24; ++ro) t2[pix * 24 + ro] = acc[ro];

    // ---------- conv1x1 24->192 + LeakyReLU pool partials ----------
    __syncthreads();
    float* t2l = (float*)smu;            // [256][28] floats = 28,672 B
#pragma unroll
    for (int ro = 0; ro < 24; ++ro) t2l[tid * 28 + ro] = acc[ro];
    __syncthreads();
    if (tid < 192) {
      float wr3[24];
#pragma unroll
      for (int i2 = 0; i2 < 24; ++i2) wr3[i2] = c3w[tid * 24 + i2];
      float b3 = c3b[tid];
      float ps = 0.f;
      for (int p = 0; p < 256; ++p) {
        const float4v* rp = reinterpret_cast<const float4v*>(&t2l[p * 28]);
        float a = b3;
#pragma unroll
        for (int v = 0; v < 6; ++v) {
          float4v q = rp[v];
          a += q[0] * wr3[v * 4] + q[1] * wr3[v * 4 + 1] + q[2] * wr3[v * 4 + 2] + q[3] * wr3[v * 4 + 3];
        }
        ps += (a < 0.f) ? 0.2f * a : a;
      }
      atomicAdd(&s0[b * 192 + tid], ps);
    }
    return;
  }

  // ---------- MFMA MLP: 64 tokens, LN2 + fc1 + GELU + fc2 + residual ----------
  // xl @0: [64][200] bf16 (25,600 B); hh @25600: [64][392] bf16 (50,176 B)
  bf16 (*xl)[200] = reinterpret_cast<bf16(*)[200]>(smu);
  bf16 (*hh)[392] = reinterpret_cast<bf16(*)[392]>(smu + 25600);
  int wave = tid >> 6, lane = tid & 63;
  int colB = lane & 15, grp = lane >> 4;
  size_t tokbase = (size_t)(blockIdx.x - 512) * 64;

  for (int t = wave; t < 64; t += 4) {
    const float* xr = x1 + (tokbase + t) * 192;
    float v0 = xr[lane], v1 = xr[lane + 64], v2 = xr[lane + 128];
    float s = v0 + v1 + v2;
    for (int o = 32; o > 0; o >>= 1) s += __shfl_down(s, o);
    s = __shfl(s, 0);
    float m = s * (1.f / 192.f);
    float d0 = v0 - m, d1 = v1 - m, d2 = v2 - m;
    float qq = d0 * d0 + d1 * d1 + d2 * d2;
    for (int o = 32; o > 0; o >>= 1) qq += __shfl_down(qq, o);
    qq = __shfl(qq, 0);
    float inv = rsqrtf(qq * (1.f / 192.f) + 1e-5f);
    xl[t][lane]       = __float2bfloat16(d0 * inv * g[lane]       + bb[lane]);
    xl[t][lane + 64]  = __float2bfloat16(d1 * inv * g[lane + 64]  + bb[lane + 64]);
    xl[t][lane + 128] = __float2bfloat16(d2 * inv * g[lane + 128] + bb[lane + 128]);
  }
  __syncthreads();

  // A-frags for token-tiles 0,1 cached in regs; tiles 2,3 read from LDS per use
  short8 a1f[6][2];
#pragma unroll
  for (int kk = 0; kk < 6; ++kk) {
    a1f[kk][0] = lds8(&xl[colB][kk * 32 + 8 * grp]);
    a1f[kk][1] = lds8(&xl[16 + colB][kk * 32 + 8 * grp]);
  }

  float4v d[3][4];
#pragma unroll
  for (int j = 0; j < 3; ++j)
#pragma unroll
    for (int tt = 0; tt < 4; ++tt) d[j][tt] = (float4v){0, 0, 0, 0};
  int ntb = wave * 3;

  for (int ph = 0; ph < 2; ++ph) {
    if (ph) __syncthreads();  // prior fc2 reads of hh complete before overwrite
    // fc1 half: 24 N-tiles (384 cols), 6 per wave, each over 4 token-tiles
    for (int nn = 0; nn < 6; ++nn) {
      int ntl = wave * 6 + nn;                 // local tile 0..23
      int colg = ph * 384 + ntl * 16 + colB;   // global fc1 col
      float4v c0 = {0,0,0,0}, c1 = {0,0,0,0}, c2 = {0,0,0,0}, c3 = {0,0,0,0};
#pragma unroll
      for (int kk = 0; kk < 6; ++kk) {
        short8 bw = glb8(w1 + (size_t)colg * 192 + kk * 32 + 8 * grp);
        c0 = __builtin_amdgcn_mfma_f32_16x16x32_bf16(a1f[kk][0], bw, c0, 0, 0, 0);
        c1 = __builtin_amdgcn_mfma_f32_16x16x32_bf16(a1f[kk][1], bw, c1, 0, 0, 0);
        c2 = __builtin_amdgcn_mfma_f32_16x16x32_bf16(lds8(&xl[32 + colB][kk * 32 + 8 * grp]), bw, c2, 0, 0, 0);
        c3 = __builtin_amdgcn_mfma_f32_16x16x32_bf16(lds8(&xl[48 + colB][kk * 32 + 8 * grp]), bw, c3, 0, 0, 0);
      }
      float bias = b1[colg];
      int coll = ntl * 16 + colB;
#pragma unroll
      for (int r = 0; r < 4; ++r) {
        float v0 = c0[r] + bias;
        float v1 = c1[r] + bias;
        float v2 = c2[r] + bias;
        float v3 = c3[r] + bias;
        v0 = v0 * 0.5f * (1.f + erff(v0 * 0.70710678118654752f));
        v1 = v1 * 0.5f * (1.f + erff(v1 * 0.70710678118654752f));
        v2 = v2 * 0.5f * (1.f + erff(v2 * 0.70710678118654752f));
        v3 = v3 * 0.5f * (1.f + erff(v3 * 0.70710678118654752f));
        hh[4 * grp + r][coll]      = __float2bfloat16(v0);
        hh[16 + 4 * grp + r][coll] = __float2bfloat16(v1);
        hh[32 + 4 * grp + r][coll] = __float2bfloat16(v2);
        hh[48 + 4 * grp + r][coll] = __float2bfloat16(v3);
      }
    }
    __syncthreads();
    // fc2 partial over this half's 384 K, all 4 token-tiles
    for (int kk = 0; kk < 12; ++kk) {
      int kol = kk * 32 + 8 * grp;
      int kog = ph * 384 + kol;
      short8 h0 = lds8(&hh[colB][kol]);
      short8 h1 = lds8(&hh[16 + colB][kol]);
      short8 h2 = lds8(&hh[32 + colB][kol]);
      short8 h3 = lds8(&hh[48 + colB][kol]);
#pragma unroll
      for (int j = 0; j < 3; ++j) {
        short8 bw = glb8(w2 + (size_t)((ntb + j) * 16 + colB) * 768 + kog);
        d[j][0] = __builtin_amdgcn_mfma_f32_16x16x32_bf16(h0, bw, d[j][0], 0, 0, 0);
        d[j][1] = __builtin_amdgcn_mfma_f32_16x16x32_bf16(h1, bw, d[j][1], 0, 0, 0);
        d[j][2] = __builtin_amdgcn_mfma_f32_16x16x32_bf16(h2, bw, d[j][2], 0, 0, 0);
        d[j][3] = __builtin_amdgcn_mfma_f32_16x16x32_bf16(h3, bw, d[j][3], 0, 0, 0);
      }
    }
  }

#pragma unroll
  for (int j = 0; j < 3; ++j) {
    int col = (ntb + j) * 16 + colB;
    float bias = b2[col];
#pragma unroll
    for (int tt = 0; tt < 4; ++tt) {
#pragma unroll
      for (int r = 0; r < 4; ++r) {
        size_t p = (tokbase + tt * 16 + 4 * grp + r) * 192 + col;
        x1[p] += d[j][tt][r] + bias;
      }
    }
  }
}

// ---------------- FUSED: SE gate + conv1x1 recompute + out += y*gate ----------------
__global__ __launch_bounds__(192) void k_final3(float* __restrict__ out, const float* __restrict__ t2,
                                                const float* __restrict__ c3w, const float* __restrict__ c3b,
                                                const float* __restrict__ s0, const float* __restrict__ w1se,
                                                const float* __restrict__ w2se) {
  __shared__ float mean[192];
  __shared__ float tt[24];
  __shared__ __align__(16) float t2l[64 * 24];
  int b = blockIdx.x >> 10;
  int chunk = blockIdx.x & 1023;
  int tid = threadIdx.x;  // 0..191
  mean[tid] = s0[b * 192 + tid] * (1.f / 65536.f);
  size_t pix0 = (size_t)b * 65536 + chunk * 64;
  for (int idx = tid; idx < 1536; idx += 192) t2l[idx] = t2[pix0 * 24 + idx];
  __syncthreads();
  if (tid < 24) {
    float a = 0.f;
    for (int c = 0; c < 192; ++c) a += mean[c] * w1se[tid * 192 + c];
    tt[tid] = fmaxf(a, 0.f);
  }
  __syncthreads();
  float a = 0.f;
#pragma unroll
  for (int r = 0; r < 24; ++r) a += tt[r] * w2se[tid * 24 + r];
  float gate = 1.f / (1.f + expf(-a));

  float wr3[24];
#pragma unroll
  for (int i = 0; i < 24; ++i) wr3[i] = c3w[tid * 24 + i];
  float b3 = c3b[tid];
  for (int p = 0; p < 64; ++p) {
    const float4v* rp = reinterpret_cast<const float4v*>(&t2l[p * 24]);
    float acc = b3;
#pragma unroll
    for (int v = 0; v < 6; ++v) {
      float4v q = rp[v];
      acc += q[0] * wr3[v * 4] + q[1] * wr3[v * 4 + 1] + q[2] * wr3[v * 4 + 2] + q[3] * wr3[v * 4 + 3];
    }
    if (acc < 0.f) acc *= 0.2f;
    out[(pix0 + p) * 192 + tid] += acc * gate;
  }
}

extern "C" void kernel_launch(void* const* d_in, const int* in_sizes, int n_in,
                              void* d_out, int out_size, void* d_ws, size_t ws_size,
                              hipStream_t stream) {
  const float* x     = (const float*)d_in[0];
  const float* n1g   = (const float*)d_in[1];
  const float* n1b   = (const float*)d_in[2];
  const float* qkvw  = (const float*)d_in[3];
  const float* qkvb  = (const float*)d_in[4];
  const float* rpb   = (const float*)d_in[5];
  const float* projw = (const float*)d_in[6];
  const float* projb = (const float*)d_in[7];
  const float* n2g   = (const float*)d_in[8];
  const float* n2b   = (const float*)d_in[9];
  const float* w1    = (const float*)d_in[10];
  const float* b1    = (const float*)d_in[11];
  const float* w2    = (const float*)d_in[12];
  const float* b2    = (const float*)d_in[13];
  const float* c1w   = (const float*)d_in[14];
  const float* c1b   = (const float*)d_in[15];
  const float* c2w   = (const float*)d_in[16];
  const float* c2b   = (const float*)d_in[17];
  const float* c3w   = (const float*)d_in[18];
  const float* c3b   = (const float*)d_in[19];
  const float* sfc1  = (const float*)d_in[20];
  const float* sfc2  = (const float*)d_in[21];
  float* out = (float*)d_out;

  if (ws_size < WS_NEEDED) return;

  char* ws = (char*)d_ws;
  float* t1   = (float*)(ws + OFF_T1);
  float* t2   = (float*)(ws + OFF_T2);
  float* s0   = (float*)(ws + OFF_S0);
  bf16*  wqkv = (bf16*)(ws + OFF_WQKV);
  bf16*  wprj = (bf16*)(ws + OFF_WPRJ);
  bf16*  wfc1 = (bf16*)(ws + OFF_WFC1);
  bf16*  wfc2 = (bf16*)(ws + OFF_WFC2);
  bf16*  c1wb = (bf16*)(ws + OFF_C1WB);

  hipFuncSetAttribute((const void*)k_mlp_lce2, hipFuncAttributeMaxDynamicSharedMemorySize, 75776);

  // weight converts + c1wb zero-pad + s0 zero, one dispatch
  k_f2b_all<<<1754, 256, 0, stream>>>(qkvw, projw, w1, w2, c1w,
                                      wqkv, wprj, wfc1, wfc2, c1wb, s0);

  // fused attention + LN1 + LCE conv1 (t1), writes x1 into d_out
  k_attn2<<<2048, 256, 0, stream>>>(x, n1g, n1b, wqkv, qkvb, rpb, wprj, projb,
                                    c1wb, c1b, t1, out);
  // FUSED: LCE conv3x3 + pool (blocks 0..511) | 64-token MLP (blocks 512..2559)
  k_mlp_lce2<<<2560, 256, 75776, stream>>>(out, n2g, n2b, wfc1, b1, wfc2, b2,
                                           t1, c2w, c2b, t2, c3w, c3b, s0);
  // FUSED: SE gate + conv1x1 recompute + out += y*gate
  k_final3<<<2048, 192, 0, stream>>>(out, t2, c3w, c3b, s0, sfc1, sfc2);
}